// Round 2
// baseline (11807.674 us; speedup 1.0000x reference)
//
#include <hip/hip_runtime.h>
#include <hip/hip_bf16.h>
#include <math.h>

// ---------------------------------------------------------------------------
// Block_38543036514772: VMAE spatio-temporal adapter block on MI355X (gfx950)
// All inputs/outputs are float32 (per reference). Activations live in ws as
// row-major [rows, feat] f32. Head h occupies columns [h*64, (h+1)*64).
// ---------------------------------------------------------------------------

typedef __bf16 bf16_t;
typedef bf16_t bf16x4 __attribute__((ext_vector_type(4)));
typedef bf16_t bf16x8 __attribute__((ext_vector_type(8)));
typedef float  f32x4  __attribute__((ext_vector_type(4)));

// ---------------------------------------------------------------------------
// GEMM: Y[M,N] = act(X[M,K] * W[N,K]^T + bias[N]) (+ res1) (+ res2_scale*res2)
// X f32, W f32 (row-major [N,K] torch-style), converted to bf16 in staging.
// Tile 64x64, BK=64, 256 threads = 4 waves (2x2), each wave 32x32 via
// 2x2 mfma_f32_16x16x32_bf16. LDS rows padded to 72 bf16 (2-way = free).
// Requires M%64==0, N%64==0, K%64==0 (true for all calls here).
// ---------------------------------------------------------------------------
template<bool GELU>
__global__ __launch_bounds__(256) void gemm_bt(
    const float* __restrict__ X, const float* __restrict__ W,
    const float* __restrict__ bias,
    const float* __restrict__ res1, const float* __restrict__ res2,
    float res2_scale,
    float* __restrict__ Y, int M, int N, int K)
{
    __shared__ bf16_t As[64][72];
    __shared__ bf16_t Bs[64][72];
    const int tid  = threadIdx.x;
    const int n0   = blockIdx.x * 64;
    const int m0   = blockIdx.y * 64;
    const int wave = tid >> 6, lane = tid & 63;
    const int wm   = (wave & 1) * 32, wn = (wave >> 1) * 32;
    const int l15  = lane & 15, lq = lane >> 4;

    f32x4 acc[2][2] = {};

    const int sr = tid >> 4;          // staging: 16 rows x 16 colgroups(x4 f32)
    const int sc4 = (tid & 15) * 4;

    for (int k0 = 0; k0 < K; k0 += 64) {
#pragma unroll
        for (int i = 0; i < 4; ++i) {
            const int row = sr + i * 16;
            const float4 xv = *reinterpret_cast<const float4*>(
                X + (size_t)(m0 + row) * K + k0 + sc4);
            bf16x4 p;
            p[0] = (bf16_t)xv.x; p[1] = (bf16_t)xv.y;
            p[2] = (bf16_t)xv.z; p[3] = (bf16_t)xv.w;
            *reinterpret_cast<bf16x4*>(&As[row][sc4]) = p;
        }
#pragma unroll
        for (int i = 0; i < 4; ++i) {
            const int row = sr + i * 16;
            const float4 wv = *reinterpret_cast<const float4*>(
                W + (size_t)(n0 + row) * K + k0 + sc4);
            bf16x4 p;
            p[0] = (bf16_t)wv.x; p[1] = (bf16_t)wv.y;
            p[2] = (bf16_t)wv.z; p[3] = (bf16_t)wv.w;
            *reinterpret_cast<bf16x4*>(&Bs[row][sc4]) = p;
        }
        __syncthreads();
#pragma unroll
        for (int kk = 0; kk < 64; kk += 32) {
            bf16x8 a0 = *reinterpret_cast<const bf16x8*>(&As[wm +      l15][kk + lq * 8]);
            bf16x8 a1 = *reinterpret_cast<const bf16x8*>(&As[wm + 16 + l15][kk + lq * 8]);
            bf16x8 b0 = *reinterpret_cast<const bf16x8*>(&Bs[wn +      l15][kk + lq * 8]);
            bf16x8 b1 = *reinterpret_cast<const bf16x8*>(&Bs[wn + 16 + l15][kk + lq * 8]);
            acc[0][0] = __builtin_amdgcn_mfma_f32_16x16x32_bf16(a0, b0, acc[0][0], 0, 0, 0);
            acc[0][1] = __builtin_amdgcn_mfma_f32_16x16x32_bf16(a0, b1, acc[0][1], 0, 0, 0);
            acc[1][0] = __builtin_amdgcn_mfma_f32_16x16x32_bf16(a1, b0, acc[1][0], 0, 0, 0);
            acc[1][1] = __builtin_amdgcn_mfma_f32_16x16x32_bf16(a1, b1, acc[1][1], 0, 0, 0);
        }
        __syncthreads();
    }

#pragma unroll
    for (int mt = 0; mt < 2; ++mt)
#pragma unroll
    for (int nt = 0; nt < 2; ++nt) {
        const int gn = n0 + wn + nt * 16 + l15;   // C/D: col = lane&15
        const float bv = bias[gn];
#pragma unroll
        for (int i = 0; i < 4; ++i) {
            const int gm = m0 + wm + mt * 16 + lq * 4 + i;  // row = quad*4+reg
            float v = acc[mt][nt][i] + bv;
            if (GELU) v = 0.5f * v * (1.0f + erff(v * 0.70710678118654752f));
            const size_t off = (size_t)gm * N + gn;
            if (res1) v += res1[off];
            if (res2) v += res2_scale * res2[off];
            Y[off] = v;
        }
    }
}

// ---------------------------------------------------------------------------
// Generic attention: one block per (batch, head, query-row).
// Q[b*nq+qi, hoff+d], K/V[b*nk+j, hoff+d]; softmax over nk keys in f32 LDS.
// ---------------------------------------------------------------------------
__global__ __launch_bounds__(256) void attn_k(
    const float* __restrict__ Q, int ldq,
    const float* __restrict__ Kp, int ldk,
    const float* __restrict__ Vp, int ldv,
    float* __restrict__ O, int ldo,
    int nq, int nk, float scale)
{
    __shared__ float sc[1568];
    __shared__ float qv[64];
    __shared__ float red[256];
    __shared__ float s_inv;
    const int tid = threadIdx.x;
    const int bx  = blockIdx.x;
    const int qi  = bx % nq;
    const int t1  = bx / nq;
    const int h   = t1 % 12;
    const int b   = t1 / 12;
    const int hoff = h * 64;
    const size_t qrow = (size_t)b * nq + qi;
    if (tid < 64) qv[tid] = Q[qrow * ldq + hoff + tid];
    __syncthreads();

    const int wave = tid >> 6, lane = tid & 63;
    const size_t kbase = (size_t)b * nk;
    for (int j = wave; j < nk; j += 4) {
        float p = Kp[(kbase + j) * ldk + hoff + lane] * qv[lane];
#pragma unroll
        for (int off = 32; off > 0; off >>= 1) p += __shfl_xor(p, off);
        if (lane == 0) sc[j] = p * scale;
    }
    __syncthreads();

    float lm = -INFINITY;
    for (int j = tid; j < nk; j += 256) lm = fmaxf(lm, sc[j]);
    red[tid] = lm; __syncthreads();
    for (int s = 128; s > 0; s >>= 1) {
        if (tid < s) red[tid] = fmaxf(red[tid], red[tid + s]);
        __syncthreads();
    }
    const float mx = red[0];
    __syncthreads();
    float ls = 0.f;
    for (int j = tid; j < nk; j += 256) { float e = expf(sc[j] - mx); sc[j] = e; ls += e; }
    red[tid] = ls; __syncthreads();
    for (int s = 128; s > 0; s >>= 1) {
        if (tid < s) red[tid] += red[tid + s];
        __syncthreads();
    }
    if (tid == 0) s_inv = 1.0f / red[0];
    __syncthreads();

    const int d = tid & 63, slice = tid >> 6;
    float acc = 0.f;
    for (int j = slice; j < nk; j += 4)
        acc += sc[j] * Vp[(kbase + j) * ldv + hoff + d];
    red[tid] = acc; __syncthreads();
    if (tid < 64) {
        float o = (red[tid] + red[tid + 64] + red[tid + 128] + red[tid + 192]) * s_inv;
        O[qrow * ldo + hoff + tid] = o;
    }
}

// ---------------------------------------------------------------------------
// LayerNorm over 768 features, one block (256 thr) per row, 3 elems/thread.
// ---------------------------------------------------------------------------
__global__ __launch_bounds__(256) void ln_k(
    const float* __restrict__ x,
    const float* __restrict__ g, const float* __restrict__ bta,
    float* __restrict__ y)
{
    __shared__ float red[256], red2[256];
    __shared__ float s_m, s_r;
    const int row = blockIdx.x, tid = threadIdx.x;
    const size_t base = (size_t)row * 768;
    const float v0 = x[base + tid];
    const float v1 = x[base + tid + 256];
    const float v2 = x[base + tid + 512];
    red[tid]  = v0 + v1 + v2;
    red2[tid] = v0 * v0 + v1 * v1 + v2 * v2;
    __syncthreads();
    for (int st = 128; st > 0; st >>= 1) {
        if (tid < st) { red[tid] += red[tid + st]; red2[tid] += red2[tid + st]; }
        __syncthreads();
    }
    if (tid == 0) {
        const float m = red[0] * (1.f / 768.f);
        const float var = red2[0] * (1.f / 768.f) - m * m;
        s_m = m; s_r = rsqrtf(var + 1e-5f);
    }
    __syncthreads();
    const float m = s_m, r = s_r;
    y[base + tid]       = (v0 - m) * r * g[tid]       + bta[tid];
    y[base + tid + 256] = (v1 - m) * r * g[tid + 256] + bta[tid + 256];
    y[base + tid + 512] = (v2 - m) * r * g[tid + 512] + bta[tid + 512];
}

// --------------------------- elementwise helpers ---------------------------
// dst[row,c] = src[row,c] + pos[row % nrep, c]
__global__ void addpos_k(const float* __restrict__ src, const float* __restrict__ pos,
                         float* __restrict__ dst, int nrep) {
    const int row = blockIdx.x, tid = threadIdx.x;
    const size_t base = (size_t)row * 768;
    const size_t pbase = (size_t)(row % nrep) * 768;
    for (int k = 0; k < 3; ++k) {
        int c = tid + k * 256;
        dst[base + c] = src[base + c] + pos[pbase + c];
    }
}
// t2s q prep: dst row (b*196+n)*8+t  <-  s_x row (b*8+t)*196+n  (+ pos_cnn[t])
__global__ void t2s_prep_q(const float* __restrict__ sx, const float* __restrict__ pos,
                           float* __restrict__ dst) {
    const int row = blockIdx.x, tid = threadIdx.x;
    const int t = row & 7, bn = row >> 3, n = bn % 196, b = bn / 196;
    const size_t src = (size_t)((b * 8 + t) * 196 + n) * 768;
    const size_t dbase = (size_t)row * 768;
    const size_t pbase = (size_t)t * 768;
    for (int k = 0; k < 3; ++k) {
        int c = tid + k * 256;
        dst[dbase + c] = sx[src + c] + pos[pbase + c];
    }
}
// t2s kv prep: dst row (b*196+n)*8+t  <-  t row b*1568 + t*196 + n  (+ pos_vmae[t])
__global__ void t2s_prep_kv(const float* __restrict__ tcur, const float* __restrict__ pos,
                            float* __restrict__ dst) {
    const int row = blockIdx.x, tid = threadIdx.x;
    const int t = row & 7, bn = row >> 3, n = bn % 196, b = bn / 196;
    const size_t src = (size_t)(b * 1568 + t * 196 + n) * 768;
    const size_t dbase = (size_t)row * 768;
    const size_t pbase = (size_t)t * 768;
    for (int k = 0; k < 3; ++k) {
        int c = tid + k * 256;
        dst[dbase + c] = tcur[src + c] + pos[pbase + c];
    }
}
// s output: out row (b*8+t)*196+n = s_x[same] + o[(b*196+n)*8+t]
__global__ void s_out_k(const float* __restrict__ sx, const float* __restrict__ o,
                        float* __restrict__ out) {
    const int row = blockIdx.x, tid = threadIdx.x;
    const int n = row % 196, bt = row / 196, t = bt & 7, b = bt >> 3;
    const size_t obase = (size_t)((b * 196 + n) * 8 + t) * 768;
    const size_t base = (size_t)row * 768;
    for (int k = 0; k < 3; ++k) {
        int c = tid + k * 256;
        out[base + c] = sx[base + c] + o[obase + c];
    }
}
// qkv bias = concat(q_bias, zeros, v_bias) f32[2304]
__global__ void build_qkv_bias(const float* __restrict__ qb,
                               const float* __restrict__ vb,
                               float* __restrict__ dst) {
    int i = blockIdx.x * 256 + threadIdx.x;
    if (i < 768) dst[i] = qb[i];
    else if (i < 1536) dst[i] = 0.f;
    else if (i < 2304) dst[i] = vb[i - 1536];
}

// ---------------------------------------------------------------------------
extern "C" void kernel_launch(void* const* d_in, const int* in_sizes, int n_in,
                              void* d_out, int out_size, void* d_ws, size_t ws_size,
                              hipStream_t stream)
{
    typedef const float* fp;
    fp s_x     = (fp)d_in[0];
    fp t_x     = (fp)d_in[1];
    fp g1      = (fp)d_in[2];
    fp bb1     = (fp)d_in[3];
    fp qkv_w   = (fp)d_in[4];
    fp q_bias  = (fp)d_in[5];
    fp v_bias  = (fp)d_in[6];
    fp aproj_w = (fp)d_in[7];
    fp aproj_b = (fp)d_in[8];
    fp sa_w1   = (fp)d_in[9];
    fp sa_b1   = (fp)d_in[10];
    fp sa_w2   = (fp)d_in[11];
    fp sa_b2   = (fp)d_in[12];
    fp s2t_pos_cnn  = (fp)d_in[13];
    fp s2t_pos_vmae = (fp)d_in[14];
    fp s2t_qw  = (fp)d_in[15];
    fp s2t_qb  = (fp)d_in[16];
    fp s2t_kvw = (fp)d_in[17];
    fp s2t_kvb = (fp)d_in[18];
    fp s2t_pw  = (fp)d_in[19];
    fp s2t_pb  = (fp)d_in[20];
    fp t2s_pos_cnn  = (fp)d_in[21];
    fp t2s_pos_vmae = (fp)d_in[22];
    fp t2s_qw  = (fp)d_in[23];
    fp t2s_qb  = (fp)d_in[24];
    fp t2s_kvw = (fp)d_in[25];
    fp t2s_kvb = (fp)d_in[26];
    fp t2s_pw  = (fp)d_in[27];
    fp t2s_pb  = (fp)d_in[28];
    fp g2      = (fp)d_in[29];
    fp bb2     = (fp)d_in[30];
    fp fc1_w   = (fp)d_in[31];
    fp fc1_b   = (fp)d_in[32];
    fp fc2_w   = (fp)d_in[33];
    fp fc2_b   = (fp)d_in[34];
    fp ma_w1   = (fp)d_in[35];
    fp ma_b1   = (fp)d_in[36];
    fp ma_w2   = (fp)d_in[37];
    fp ma_b2   = (fp)d_in[38];

    const size_t RD  = (size_t)6272 * 768;         // 4,816,896
    const size_t D32 = (size_t)6272 * 3072;
    float* ws = (float*)d_ws;
    float* C    = ws;                              // xn / kv-in / xn2
    float* D    = C + RD;                          // 6272x3072 (qkv / kv / mlp-h)
    float* E    = D + D32;                         // q / attn out
    float* F    = E + RD;                          // o1 / attn out / mad
    float* G    = F + RD;                          // running t (t1 -> t2)
    float* qkvb = G + RD;                          // f32[2304]
    float* Hb   = qkvb + 2304;                     // 6272x192 adapter hidden
    float* I    = D + (size_t)6272 * 1536;         // alias: 2nd half of D

    float* out_s = (float*)d_out;                  // [32*196, 768]
    float* out_t = out_s + RD;                     // [4*1568, 768]

    const dim3 blk(256);

    // ---- stage 1: self-attention + serial adapter ----
    ln_k<<<6272, blk, 0, stream>>>(t_x, g1, bb1, C);
    build_qkv_bias<<<9, blk, 0, stream>>>(q_bias, v_bias, qkvb);
    gemm_bt<false><<<dim3(36, 98), blk, 0, stream>>>(
        C, qkv_w, qkvb, nullptr, nullptr, 0.f, D, 6272, 2304, 768);
    attn_k<<<4 * 12 * 1568, blk, 0, stream>>>(D, 2304, D + 768, 2304, D + 1536, 2304,
                                              E, 768, 1568, 1568, 0.125f);
    gemm_bt<false><<<dim3(12, 98), blk, 0, stream>>>(
        E, aproj_w, aproj_b, nullptr, nullptr, 0.f, F, 6272, 768, 768);
    gemm_bt<true><<<dim3(3, 98), blk, 0, stream>>>(
        F, sa_w1, sa_b1, nullptr, nullptr, 0.f, Hb, 6272, 192, 768);
    // t1 = t_x + o1 + up(gelu(down(o1)))
    gemm_bt<false><<<dim3(12, 98), blk, 0, stream>>>(
        Hb, sa_w2, sa_b2, F, t_x, 1.0f, G, 6272, 768, 192);

    // ---- stage 2: S2T cross-attn ----
    addpos_k<<<6272, blk, 0, stream>>>(G, s2t_pos_vmae, I, 196);   // queries in
    addpos_k<<<6272, blk, 0, stream>>>(s_x, s2t_pos_cnn, C, 196);  // kv in
    gemm_bt<false><<<dim3(12, 98), blk, 0, stream>>>(
        I, s2t_qw, s2t_qb, nullptr, nullptr, 0.f, E, 6272, 768, 768);
    gemm_bt<false><<<dim3(24, 98), blk, 0, stream>>>(
        C, s2t_kvw, s2t_kvb, nullptr, nullptr, 0.f, D, 6272, 1536, 768);
    attn_k<<<32 * 12 * 196, blk, 0, stream>>>(E, 768, D, 1536, D + 768, 1536,
                                              F, 768, 196, 196, 0.125f);
    gemm_bt<false><<<dim3(12, 98), blk, 0, stream>>>(
        F, s2t_pw, s2t_pb, G, nullptr, 0.f, G, 6272, 768, 768);    // t2 (in place)

    // ---- stage 3: T2S cross-attn ----
    t2s_prep_q<<<6272, blk, 0, stream>>>(s_x, t2s_pos_cnn, I);
    t2s_prep_kv<<<6272, blk, 0, stream>>>(G, t2s_pos_vmae, C);
    gemm_bt<false><<<dim3(12, 98), blk, 0, stream>>>(
        I, t2s_qw, t2s_qb, nullptr, nullptr, 0.f, E, 6272, 768, 768);
    gemm_bt<false><<<dim3(24, 98), blk, 0, stream>>>(
        C, t2s_kvw, t2s_kvb, nullptr, nullptr, 0.f, D, 6272, 1536, 768);
    attn_k<<<784 * 12 * 8, blk, 0, stream>>>(E, 768, D, 1536, D + 768, 1536,
                                             F, 768, 8, 8, 0.125f);
    gemm_bt<false><<<dim3(12, 98), blk, 0, stream>>>(
        F, t2s_pw, t2s_pb, nullptr, nullptr, 0.f, I, 6272, 768, 768);
    s_out_k<<<6272, blk, 0, stream>>>(s_x, I, out_s);              // s output

    // ---- stage 4: MLP + parallel adapter ----
    ln_k<<<6272, blk, 0, stream>>>(G, g2, bb2, C);
    gemm_bt<true><<<dim3(48, 98), blk, 0, stream>>>(
        C, fc1_w, fc1_b, nullptr, nullptr, 0.f, D, 6272, 3072, 768);
    gemm_bt<true><<<dim3(3, 98), blk, 0, stream>>>(
        C, ma_w1, ma_b1, nullptr, nullptr, 0.f, Hb, 6272, 192, 768);
    gemm_bt<false><<<dim3(12, 98), blk, 0, stream>>>(
        Hb, ma_w2, ma_b2, nullptr, nullptr, 0.f, F, 6272, 768, 192);
    // t_out = t2 + mlp + 0.5*mad  (written straight to d_out)
    gemm_bt<false><<<dim3(12, 98), blk, 0, stream>>>(
        D, fc2_w, fc2_b, G, F, 0.5f, out_t, 6272, 768, 3072);
}

// Round 3
// 1689.941 us; speedup vs baseline: 6.9870x; 6.9870x over previous
//
#include <hip/hip_runtime.h>
#include <hip/hip_bf16.h>
#include <math.h>

// ---------------------------------------------------------------------------
// Block_38543036514772: VMAE spatio-temporal adapter block on MI355X (gfx950)
// All inputs/outputs are float32 (per reference). Activations live in ws as
// row-major [rows, feat] f32. Head h occupies columns [h*64, (h+1)*64).
// ---------------------------------------------------------------------------

typedef __bf16 bf16_t;
typedef bf16_t bf16x4 __attribute__((ext_vector_type(4)));
typedef bf16_t bf16x8 __attribute__((ext_vector_type(8)));
typedef float  f32x4  __attribute__((ext_vector_type(4)));

// ---------------------------------------------------------------------------
// GEMM: Y[M,N] = act(X[M,K] * W[N,K]^T + bias[N]) (+ res1) (+ res2_scale*res2)
// Tile 64x64, BK=64, 4 waves (2x2), 2x2 mfma_f32_16x16x32_bf16 per wave.
// Verified C/D layout: col = lane&15, row = (lane>>4)*4 + reg.
// ---------------------------------------------------------------------------
template<bool GELU>
__global__ __launch_bounds__(256) void gemm_bt(
    const float* __restrict__ X, const float* __restrict__ W,
    const float* __restrict__ bias,
    const float* __restrict__ res1, const float* __restrict__ res2,
    float res2_scale,
    float* __restrict__ Y, int M, int N, int K)
{
    __shared__ bf16_t As[64][72];
    __shared__ bf16_t Bs[64][72];
    const int tid  = threadIdx.x;
    const int n0   = blockIdx.x * 64;
    const int m0   = blockIdx.y * 64;
    const int wave = tid >> 6, lane = tid & 63;
    const int wm   = (wave & 1) * 32, wn = (wave >> 1) * 32;
    const int l15  = lane & 15, lq = lane >> 4;

    f32x4 acc[2][2] = {};

    const int sr = tid >> 4;          // staging: 16 rows x 16 colgroups(x4 f32)
    const int sc4 = (tid & 15) * 4;

    for (int k0 = 0; k0 < K; k0 += 64) {
#pragma unroll
        for (int i = 0; i < 4; ++i) {
            const int row = sr + i * 16;
            const float4 xv = *reinterpret_cast<const float4*>(
                X + (size_t)(m0 + row) * K + k0 + sc4);
            bf16x4 p;
            p[0] = (bf16_t)xv.x; p[1] = (bf16_t)xv.y;
            p[2] = (bf16_t)xv.z; p[3] = (bf16_t)xv.w;
            *reinterpret_cast<bf16x4*>(&As[row][sc4]) = p;
        }
#pragma unroll
        for (int i = 0; i < 4; ++i) {
            const int row = sr + i * 16;
            const float4 wv = *reinterpret_cast<const float4*>(
                W + (size_t)(n0 + row) * K + k0 + sc4);
            bf16x4 p;
            p[0] = (bf16_t)wv.x; p[1] = (bf16_t)wv.y;
            p[2] = (bf16_t)wv.z; p[3] = (bf16_t)wv.w;
            *reinterpret_cast<bf16x4*>(&Bs[row][sc4]) = p;
        }
        __syncthreads();
#pragma unroll
        for (int kk = 0; kk < 64; kk += 32) {
            bf16x8 a0 = *reinterpret_cast<const bf16x8*>(&As[wm +      l15][kk + lq * 8]);
            bf16x8 a1 = *reinterpret_cast<const bf16x8*>(&As[wm + 16 + l15][kk + lq * 8]);
            bf16x8 b0 = *reinterpret_cast<const bf16x8*>(&Bs[wn +      l15][kk + lq * 8]);
            bf16x8 b1 = *reinterpret_cast<const bf16x8*>(&Bs[wn + 16 + l15][kk + lq * 8]);
            acc[0][0] = __builtin_amdgcn_mfma_f32_16x16x32_bf16(a0, b0, acc[0][0], 0, 0, 0);
            acc[0][1] = __builtin_amdgcn_mfma_f32_16x16x32_bf16(a0, b1, acc[0][1], 0, 0, 0);
            acc[1][0] = __builtin_amdgcn_mfma_f32_16x16x32_bf16(a1, b0, acc[1][0], 0, 0, 0);
            acc[1][1] = __builtin_amdgcn_mfma_f32_16x16x32_bf16(a1, b1, acc[1][1], 0, 0, 0);
        }
        __syncthreads();
    }

#pragma unroll
    for (int mt = 0; mt < 2; ++mt)
#pragma unroll
    for (int nt = 0; nt < 2; ++nt) {
        const int gn = n0 + wn + nt * 16 + l15;
        const float bv = bias[gn];
#pragma unroll
        for (int i = 0; i < 4; ++i) {
            const int gm = m0 + wm + mt * 16 + lq * 4 + i;
            float v = acc[mt][nt][i] + bv;
            if (GELU) v = 0.5f * v * (1.0f + erff(v * 0.70710678118654752f));
            const size_t off = (size_t)gm * N + gn;
            if (res1) v += res1[off];
            if (res2) v += res2_scale * res2[off];
            Y[off] = v;
        }
    }
}

// ---------------------------------------------------------------------------
// MFMA flash attention. One block = (q-tile of 64, head, group).
// Q/K/V rows strided ldq/ldk/ldv, head offset blockIdx.y*64, hd=64.
// Online softmax over k-tiles of 64; partial tiles masked by key index.
// ---------------------------------------------------------------------------
__global__ __launch_bounds__(256) void flash_k(
    const float* __restrict__ Q, int ldq,
    const float* __restrict__ Kp, int ldk,
    const float* __restrict__ Vp, int ldv,
    float* __restrict__ O, int ldo,
    int nq, int nk, float scale)
{
    __shared__ bf16_t Qs[64][72], Ks[64][72], Vs[64][72], Ps[64][72];
    __shared__ float sc[64][65];            // stride 65: <=2-way bank aliasing
    __shared__ float mS[64], lS[64], aS[64];

    const int tid  = threadIdx.x;
    const int q0   = blockIdx.x * 64;
    const int hoff = blockIdx.y * 64;
    const int g    = blockIdx.z;
    const int wave = tid >> 6, lane = tid & 63;
    const int wm   = (wave & 1) * 32, wn = (wave >> 1) * 32;
    const int l15  = lane & 15, lq = lane >> 4;
    const int sr   = tid >> 4, sc4 = (tid & 15) * 4;

    // stage Q tile (pre-scaled; rows clamped so OOB q-rows read valid memory)
#pragma unroll
    for (int i = 0; i < 4; ++i) {
        const int row = sr + i * 16;
        int qrow = q0 + row; if (qrow > nq - 1) qrow = nq - 1;
        const float4 v = *reinterpret_cast<const float4*>(
            Q + ((size_t)g * nq + qrow) * ldq + hoff + sc4);
        bf16x4 p;
        p[0] = (bf16_t)(v.x * scale); p[1] = (bf16_t)(v.y * scale);
        p[2] = (bf16_t)(v.z * scale); p[3] = (bf16_t)(v.w * scale);
        *reinterpret_cast<bf16x4*>(&Qs[row][sc4]) = p;
    }
    if (tid < 64) { mS[tid] = -INFINITY; lS[tid] = 0.f; }
    f32x4 acc_o[2][2] = {};
    __syncthreads();

    for (int kk0 = 0; kk0 < nk; kk0 += 64) {
        // stage K tile and V tile (V transposed: Vs[dim][key])
#pragma unroll
        for (int i = 0; i < 4; ++i) {
            const int row = sr + i * 16;
            int krow = kk0 + row; if (krow > nk - 1) krow = nk - 1;
            const size_t rbase = (size_t)g * nk + krow;
            const float4 kv = *reinterpret_cast<const float4*>(
                Kp + rbase * ldk + hoff + sc4);
            bf16x4 pk;
            pk[0] = (bf16_t)kv.x; pk[1] = (bf16_t)kv.y;
            pk[2] = (bf16_t)kv.z; pk[3] = (bf16_t)kv.w;
            *reinterpret_cast<bf16x4*>(&Ks[row][sc4]) = pk;
            const float4 vv = *reinterpret_cast<const float4*>(
                Vp + rbase * ldv + hoff + sc4);
            Vs[sc4 + 0][row] = (bf16_t)vv.x;
            Vs[sc4 + 1][row] = (bf16_t)vv.y;
            Vs[sc4 + 2][row] = (bf16_t)vv.z;
            Vs[sc4 + 3][row] = (bf16_t)vv.w;
        }
        __syncthreads();

        // S = Q * K^T   (64x64)
        f32x4 s[2][2] = {};
#pragma unroll
        for (int kk = 0; kk < 64; kk += 32) {
            bf16x8 a0 = *reinterpret_cast<const bf16x8*>(&Qs[wm +      l15][kk + lq * 8]);
            bf16x8 a1 = *reinterpret_cast<const bf16x8*>(&Qs[wm + 16 + l15][kk + lq * 8]);
            bf16x8 b0 = *reinterpret_cast<const bf16x8*>(&Ks[wn +      l15][kk + lq * 8]);
            bf16x8 b1 = *reinterpret_cast<const bf16x8*>(&Ks[wn + 16 + l15][kk + lq * 8]);
            s[0][0] = __builtin_amdgcn_mfma_f32_16x16x32_bf16(a0, b0, s[0][0], 0, 0, 0);
            s[0][1] = __builtin_amdgcn_mfma_f32_16x16x32_bf16(a0, b1, s[0][1], 0, 0, 0);
            s[1][0] = __builtin_amdgcn_mfma_f32_16x16x32_bf16(a1, b0, s[1][0], 0, 0, 0);
            s[1][1] = __builtin_amdgcn_mfma_f32_16x16x32_bf16(a1, b1, s[1][1], 0, 0, 0);
        }
#pragma unroll
        for (int mt = 0; mt < 2; ++mt)
#pragma unroll
        for (int nt = 0; nt < 2; ++nt)
#pragma unroll
        for (int i = 0; i < 4; ++i)
            sc[wm + mt * 16 + lq * 4 + i][wn + nt * 16 + l15] = s[mt][nt][i];
        __syncthreads();

        // row softmax (4 threads per row, 16 cols each)
        {
            const int row = tid >> 2, c0 = (tid & 3) * 16;
            float lmax = -INFINITY;
#pragma unroll
            for (int c = 0; c < 16; ++c)
                if (kk0 + c0 + c < nk) lmax = fmaxf(lmax, sc[row][c0 + c]);
            lmax = fmaxf(lmax, __shfl_xor(lmax, 1));
            lmax = fmaxf(lmax, __shfl_xor(lmax, 2));
            const float mold = mS[row];
            const float mnew = fmaxf(mold, lmax);
            const float alpha = expf(mold - mnew);
            float psum = 0.f;
#pragma unroll
            for (int c = 0; c < 16; ++c) {
                float p = 0.f;
                if (kk0 + c0 + c < nk) p = expf(sc[row][c0 + c] - mnew);
                Ps[row][c0 + c] = (bf16_t)p;
                psum += p;
            }
            psum += __shfl_xor(psum, 1);
            psum += __shfl_xor(psum, 2);
            const float lnew = lS[row] * alpha + psum;   // all 4 threads identical
            mS[row] = mnew; lS[row] = lnew; aS[row] = alpha;
        }
        __syncthreads();

        // O = O*alpha + P*V
#pragma unroll
        for (int mt = 0; mt < 2; ++mt)
#pragma unroll
        for (int i = 0; i < 4; ++i) {
            const float a = aS[wm + mt * 16 + lq * 4 + i];
            acc_o[mt][0][i] *= a;
            acc_o[mt][1][i] *= a;
        }
#pragma unroll
        for (int kk = 0; kk < 64; kk += 32) {
            bf16x8 a0 = *reinterpret_cast<const bf16x8*>(&Ps[wm +      l15][kk + lq * 8]);
            bf16x8 a1 = *reinterpret_cast<const bf16x8*>(&Ps[wm + 16 + l15][kk + lq * 8]);
            bf16x8 b0 = *reinterpret_cast<const bf16x8*>(&Vs[wn +      l15][kk + lq * 8]);
            bf16x8 b1 = *reinterpret_cast<const bf16x8*>(&Vs[wn + 16 + l15][kk + lq * 8]);
            acc_o[0][0] = __builtin_amdgcn_mfma_f32_16x16x32_bf16(a0, b0, acc_o[0][0], 0, 0, 0);
            acc_o[0][1] = __builtin_amdgcn_mfma_f32_16x16x32_bf16(a0, b1, acc_o[0][1], 0, 0, 0);
            acc_o[1][0] = __builtin_amdgcn_mfma_f32_16x16x32_bf16(a1, b0, acc_o[1][0], 0, 0, 0);
            acc_o[1][1] = __builtin_amdgcn_mfma_f32_16x16x32_bf16(a1, b1, acc_o[1][1], 0, 0, 0);
        }
        __syncthreads();
    }

    // epilogue: O / l
#pragma unroll
    for (int mt = 0; mt < 2; ++mt)
#pragma unroll
    for (int nt = 0; nt < 2; ++nt) {
        const int col = wn + nt * 16 + l15;
#pragma unroll
        for (int i = 0; i < 4; ++i) {
            const int r = wm + mt * 16 + lq * 4 + i;
            const int qrow = q0 + r;
            if (qrow < nq)
                O[((size_t)g * nq + qrow) * ldo + hoff + col] = acc_o[mt][nt][i] / lS[r];
        }
    }
}

// ---------------------------------------------------------------------------
// Scalar attention (kept for T2S where nk=8): one block per (group, head, q).
// ---------------------------------------------------------------------------
__global__ __launch_bounds__(256) void attn_k(
    const float* __restrict__ Q, int ldq,
    const float* __restrict__ Kp, int ldk,
    const float* __restrict__ Vp, int ldv,
    float* __restrict__ O, int ldo,
    int nq, int nk, float scale)
{
    __shared__ float sc[64];
    __shared__ float qv[64];
    __shared__ float red[256];
    __shared__ float s_inv;
    const int tid = threadIdx.x;
    const int bx  = blockIdx.x;
    const int qi  = bx % nq;
    const int t1  = bx / nq;
    const int h   = t1 % 12;
    const int b   = t1 / 12;
    const int hoff = h * 64;
    const size_t qrow = (size_t)b * nq + qi;
    if (tid < 64) qv[tid] = Q[qrow * ldq + hoff + tid];
    __syncthreads();

    const int wave = tid >> 6, lane = tid & 63;
    const size_t kbase = (size_t)b * nk;
    for (int j = wave; j < nk; j += 4) {
        float p = Kp[(kbase + j) * ldk + hoff + lane] * qv[lane];
#pragma unroll
        for (int off = 32; off > 0; off >>= 1) p += __shfl_xor(p, off);
        if (lane == 0) sc[j] = p * scale;
    }
    __syncthreads();

    float lm = -INFINITY;
    for (int j = tid; j < nk; j += 256) lm = fmaxf(lm, sc[j]);
    red[tid] = lm; __syncthreads();
    for (int s = 128; s > 0; s >>= 1) {
        if (tid < s) red[tid] = fmaxf(red[tid], red[tid + s]);
        __syncthreads();
    }
    const float mx = red[0];
    __syncthreads();
    float ls = 0.f;
    for (int j = tid; j < nk; j += 256) { float e = expf(sc[j] - mx); sc[j] = e; ls += e; }
    red[tid] = ls; __syncthreads();
    for (int s = 128; s > 0; s >>= 1) {
        if (tid < s) red[tid] += red[tid + s];
        __syncthreads();
    }
    if (tid == 0) s_inv = 1.0f / red[0];
    __syncthreads();

    const int d = tid & 63, slice = tid >> 6;
    float acc = 0.f;
    for (int j = slice; j < nk; j += 4)
        acc += sc[j] * Vp[(kbase + j) * ldv + hoff + d];
    red[tid] = acc; __syncthreads();
    if (tid < 64) {
        float o = (red[tid] + red[tid + 64] + red[tid + 128] + red[tid + 192]) * s_inv;
        O[qrow * ldo + hoff + tid] = o;
    }
}

// ---------------------------------------------------------------------------
// LayerNorm over 768 features, one block (256 thr) per row.
// ---------------------------------------------------------------------------
__global__ __launch_bounds__(256) void ln_k(
    const float* __restrict__ x,
    const float* __restrict__ g, const float* __restrict__ bta,
    float* __restrict__ y)
{
    __shared__ float red[256], red2[256];
    __shared__ float s_m, s_r;
    const int row = blockIdx.x, tid = threadIdx.x;
    const size_t base = (size_t)row * 768;
    const float v0 = x[base + tid];
    const float v1 = x[base + tid + 256];
    const float v2 = x[base + tid + 512];
    red[tid]  = v0 + v1 + v2;
    red2[tid] = v0 * v0 + v1 * v1 + v2 * v2;
    __syncthreads();
    for (int st = 128; st > 0; st >>= 1) {
        if (tid < st) { red[tid] += red[tid + st]; red2[tid] += red2[tid + st]; }
        __syncthreads();
    }
    if (tid == 0) {
        const float m = red[0] * (1.f / 768.f);
        const float var = red2[0] * (1.f / 768.f) - m * m;
        s_m = m; s_r = rsqrtf(var + 1e-5f);
    }
    __syncthreads();
    const float m = s_m, r = s_r;
    y[base + tid]       = (v0 - m) * r * g[tid]       + bta[tid];
    y[base + tid + 256] = (v1 - m) * r * g[tid + 256] + bta[tid + 256];
    y[base + tid + 512] = (v2 - m) * r * g[tid + 512] + bta[tid + 512];
}

// --------------------------- elementwise helpers ---------------------------
__global__ void addpos_k(const float* __restrict__ src, const float* __restrict__ pos,
                         float* __restrict__ dst, int nrep) {
    const int row = blockIdx.x, tid = threadIdx.x;
    const size_t base = (size_t)row * 768;
    const size_t pbase = (size_t)(row % nrep) * 768;
    for (int k = 0; k < 3; ++k) {
        int c = tid + k * 256;
        dst[base + c] = src[base + c] + pos[pbase + c];
    }
}
__global__ void t2s_prep_q(const float* __restrict__ sx, const float* __restrict__ pos,
                           float* __restrict__ dst) {
    const int row = blockIdx.x, tid = threadIdx.x;
    const int t = row & 7, bn = row >> 3, n = bn % 196, b = bn / 196;
    const size_t src = (size_t)((b * 8 + t) * 196 + n) * 768;
    const size_t dbase = (size_t)row * 768;
    const size_t pbase = (size_t)t * 768;
    for (int k = 0; k < 3; ++k) {
        int c = tid + k * 256;
        dst[dbase + c] = sx[src + c] + pos[pbase + c];
    }
}
__global__ void t2s_prep_kv(const float* __restrict__ tcur, const float* __restrict__ pos,
                            float* __restrict__ dst) {
    const int row = blockIdx.x, tid = threadIdx.x;
    const int t = row & 7, bn = row >> 3, n = bn % 196, b = bn / 196;
    const size_t src = (size_t)(b * 1568 + t * 196 + n) * 768;
    const size_t dbase = (size_t)row * 768;
    const size_t pbase = (size_t)t * 768;
    for (int k = 0; k < 3; ++k) {
        int c = tid + k * 256;
        dst[dbase + c] = tcur[src + c] + pos[pbase + c];
    }
}
__global__ void s_out_k(const float* __restrict__ sx, const float* __restrict__ o,
                        float* __restrict__ out) {
    const int row = blockIdx.x, tid = threadIdx.x;
    const int n = row % 196, bt = row / 196, t = bt & 7, b = bt >> 3;
    const size_t obase = (size_t)((b * 196 + n) * 8 + t) * 768;
    const size_t base = (size_t)row * 768;
    for (int k = 0; k < 3; ++k) {
        int c = tid + k * 256;
        out[base + c] = sx[base + c] + o[obase + c];
    }
}
__global__ void build_qkv_bias(const float* __restrict__ qb,
                               const float* __restrict__ vb,
                               float* __restrict__ dst) {
    int i = blockIdx.x * 256 + threadIdx.x;
    if (i < 768) dst[i] = qb[i];
    else if (i < 1536) dst[i] = 0.f;
    else if (i < 2304) dst[i] = vb[i - 1536];
}

// ---------------------------------------------------------------------------
extern "C" void kernel_launch(void* const* d_in, const int* in_sizes, int n_in,
                              void* d_out, int out_size, void* d_ws, size_t ws_size,
                              hipStream_t stream)
{
    typedef const float* fp;
    fp s_x     = (fp)d_in[0];
    fp t_x     = (fp)d_in[1];
    fp g1      = (fp)d_in[2];
    fp bb1     = (fp)d_in[3];
    fp qkv_w   = (fp)d_in[4];
    fp q_bias  = (fp)d_in[5];
    fp v_bias  = (fp)d_in[6];
    fp aproj_w = (fp)d_in[7];
    fp aproj_b = (fp)d_in[8];
    fp sa_w1   = (fp)d_in[9];
    fp sa_b1   = (fp)d_in[10];
    fp sa_w2   = (fp)d_in[11];
    fp sa_b2   = (fp)d_in[12];
    fp s2t_pos_cnn  = (fp)d_in[13];
    fp s2t_pos_vmae = (fp)d_in[14];
    fp s2t_qw  = (fp)d_in[15];
    fp s2t_qb  = (fp)d_in[16];
    fp s2t_kvw = (fp)d_in[17];
    fp s2t_kvb = (fp)d_in[18];
    fp s2t_pw  = (fp)d_in[19];
    fp s2t_pb  = (fp)d_in[20];
    fp t2s_pos_cnn  = (fp)d_in[21];
    fp t2s_pos_vmae = (fp)d_in[22];
    fp t2s_qw  = (fp)d_in[23];
    fp t2s_qb  = (fp)d_in[24];
    fp t2s_kvw = (fp)d_in[25];
    fp t2s_kvb = (fp)d_in[26];
    fp t2s_pw  = (fp)d_in[27];
    fp t2s_pb  = (fp)d_in[28];
    fp g2      = (fp)d_in[29];
    fp bb2     = (fp)d_in[30];
    fp fc1_w   = (fp)d_in[31];
    fp fc1_b   = (fp)d_in[32];
    fp fc2_w   = (fp)d_in[33];
    fp fc2_b   = (fp)d_in[34];
    fp ma_w1   = (fp)d_in[35];
    fp ma_b1   = (fp)d_in[36];
    fp ma_w2   = (fp)d_in[37];
    fp ma_b2   = (fp)d_in[38];

    const size_t RD  = (size_t)6272 * 768;
    const size_t D32 = (size_t)6272 * 3072;
    float* ws = (float*)d_ws;
    float* C    = ws;                              // xn / kv-in / xn2
    float* D    = C + RD;                          // 6272x3072 (qkv / kv / mlp-h)
    float* E    = D + D32;                         // q / attn out
    float* F    = E + RD;                          // o1 / attn out / mad
    float* G    = F + RD;                          // running t (t1 -> t2)
    float* qkvb = G + RD;                          // f32[2304]
    float* Hb   = qkvb + 2304;                     // 6272x192 adapter hidden
    float* I    = D + (size_t)6272 * 1536;         // alias: 2nd half of D

    float* out_s = (float*)d_out;                  // [32*196, 768]
    float* out_t = out_s + RD;                     // [4*1568, 768]

    const dim3 blk(256);

    // ---- stage 1: self-attention + serial adapter ----
    ln_k<<<6272, blk, 0, stream>>>(t_x, g1, bb1, C);
    build_qkv_bias<<<9, blk, 0, stream>>>(q_bias, v_bias, qkvb);
    gemm_bt<false><<<dim3(36, 98), blk, 0, stream>>>(
        C, qkv_w, qkvb, nullptr, nullptr, 0.f, D, 6272, 2304, 768);
    flash_k<<<dim3(25, 12, 4), blk, 0, stream>>>(
        D, 2304, D + 768, 2304, D + 1536, 2304, E, 768, 1568, 1568, 0.125f);
    gemm_bt<false><<<dim3(12, 98), blk, 0, stream>>>(
        E, aproj_w, aproj_b, nullptr, nullptr, 0.f, F, 6272, 768, 768);
    gemm_bt<true><<<dim3(3, 98), blk, 0, stream>>>(
        F, sa_w1, sa_b1, nullptr, nullptr, 0.f, Hb, 6272, 192, 768);
    // t1 = t_x + o1 + up(gelu(down(o1)))
    gemm_bt<false><<<dim3(12, 98), blk, 0, stream>>>(
        Hb, sa_w2, sa_b2, F, t_x, 1.0f, G, 6272, 768, 192);

    // ---- stage 2: S2T cross-attn ----
    addpos_k<<<6272, blk, 0, stream>>>(G, s2t_pos_vmae, I, 196);   // queries in
    addpos_k<<<6272, blk, 0, stream>>>(s_x, s2t_pos_cnn, C, 196);  // kv in
    gemm_bt<false><<<dim3(12, 98), blk, 0, stream>>>(
        I, s2t_qw, s2t_qb, nullptr, nullptr, 0.f, E, 6272, 768, 768);
    gemm_bt<false><<<dim3(24, 98), blk, 0, stream>>>(
        C, s2t_kvw, s2t_kvb, nullptr, nullptr, 0.f, D, 6272, 1536, 768);
    flash_k<<<dim3(4, 12, 32), blk, 0, stream>>>(
        E, 768, D, 1536, D + 768, 1536, F, 768, 196, 196, 0.125f);
    gemm_bt<false><<<dim3(12, 98), blk, 0, stream>>>(
        F, s2t_pw, s2t_pb, G, nullptr, 0.f, G, 6272, 768, 768);    // t2 (in place)

    // ---- stage 3: T2S cross-attn ----
    t2s_prep_q<<<6272, blk, 0, stream>>>(s_x, t2s_pos_cnn, I);
    t2s_prep_kv<<<6272, blk, 0, stream>>>(G, t2s_pos_vmae, C);
    gemm_bt<false><<<dim3(12, 98), blk, 0, stream>>>(
        I, t2s_qw, t2s_qb, nullptr, nullptr, 0.f, E, 6272, 768, 768);
    gemm_bt<false><<<dim3(24, 98), blk, 0, stream>>>(
        C, t2s_kvw, t2s_kvb, nullptr, nullptr, 0.f, D, 6272, 1536, 768);
    attn_k<<<784 * 12 * 8, blk, 0, stream>>>(E, 768, D, 1536, D + 768, 1536,
                                             F, 768, 8, 8, 0.125f);
    gemm_bt<false><<<dim3(12, 98), blk, 0, stream>>>(
        F, t2s_pw, t2s_pb, nullptr, nullptr, 0.f, I, 6272, 768, 768);
    s_out_k<<<6272, blk, 0, stream>>>(s_x, I, out_s);              // s output

    // ---- stage 4: MLP + parallel adapter ----
    ln_k<<<6272, blk, 0, stream>>>(G, g2, bb2, C);
    gemm_bt<true><<<dim3(48, 98), blk, 0, stream>>>(
        C, fc1_w, fc1_b, nullptr, nullptr, 0.f, D, 6272, 3072, 768);
    gemm_bt<true><<<dim3(3, 98), blk, 0, stream>>>(
        C, ma_w1, ma_b1, nullptr, nullptr, 0.f, Hb, 6272, 192, 768);
    gemm_bt<false><<<dim3(12, 98), blk, 0, stream>>>(
        Hb, ma_w2, ma_b2, nullptr, nullptr, 0.f, F, 6272, 768, 192);
    // t_out = t2 + mlp + 0.5*mad  (written straight to d_out)
    gemm_bt<false><<<dim3(12, 98), blk, 0, stream>>>(
        D, fc2_w, fc2_b, G, F, 0.5f, out_t, 6272, 768, 3072);
}

// Round 5
// 1227.453 us; speedup vs baseline: 9.6197x; 1.3768x over previous
//
#include <hip/hip_runtime.h>
#include <hip/hip_bf16.h>
#include <math.h>

// ---------------------------------------------------------------------------
// Block_38543036514772 on MI355X (gfx950). f32 in/out; bf16 MFMA internals.
// Big GEMMs: 128x128 tile + global_load_lds(16B), bf16 A/W (m97 structure).
// Flash attn: bf16 QKV, P reuses K LDS, conflict-free V transpose.
// R5 fix: wcvt cum[] table (t2s_kvw is 294912 float4s, not 147456) — R4's
// wrong table caused a 2.25MB OOB read past fc1_w -> memory fault.
// ---------------------------------------------------------------------------

typedef __bf16 bf16_t;
typedef bf16_t bf16x4 __attribute__((ext_vector_type(4)));
typedef bf16_t bf16x8 __attribute__((ext_vector_type(8)));
typedef float  f32x4  __attribute__((ext_vector_type(4)));

typedef const __attribute__((address_space(1))) void* gas_t;
typedef __attribute__((address_space(3))) void* las_t;
__device__ __forceinline__ void async16(const void* g, void* l) {
    // LDS dest = wave-uniform base + lane*16
    __builtin_amdgcn_global_load_lds((gas_t)g, (las_t)l, 16, 0, 0);
}

#define MFMA(a,b,c) __builtin_amdgcn_mfma_f32_16x16x32_bf16((a),(b),(c),0,0,0)

// ---------------------------------------------------------------------------
// Big GEMM: Y = act(A[M,K](bf16) * W[N,K](bf16)^T + bias) (+res1) (+s*res2)
// 128x128 tile, BK=64, 4 waves (2x2 of 64x64), global_load_lds staging.
// Requires M%128==0, N%128==0, K%64==0.
// ---------------------------------------------------------------------------
template<bool GELU>
__global__ __launch_bounds__(256) void gemm128(
    const bf16_t* __restrict__ A, const bf16_t* __restrict__ W,
    const float* __restrict__ bias,
    const float* __restrict__ res1, const float* __restrict__ res2,
    float res2_scale,
    float* __restrict__ Yf, bf16_t* __restrict__ Yb,
    int M, int N, int K)
{
    __shared__ bf16_t As[128*64];
    __shared__ bf16_t Bs[128*64];
    const int tid = threadIdx.x, wave = tid >> 6, lane = tid & 63;
    const int m0 = blockIdx.y * 128, n0 = blockIdx.x * 128;
    const int wm = (wave & 1) * 64, wn = (wave >> 1) * 64;
    const int l15 = lane & 15, lq = lane >> 4;
    const int lrow = lane >> 3, lcol = (lane & 7) * 8;   // 8 rows x 64 cols / chunk

    f32x4 acc[4][4] = {};

    for (int k0 = 0; k0 < K; k0 += 64) {
#pragma unroll
        for (int c = 0; c < 4; ++c) {
            const int r = wave * 32 + c * 8;
            async16(A + (size_t)(m0 + r + lrow) * K + k0 + lcol, &As[r * 64]);
            async16(W + (size_t)(n0 + r + lrow) * K + k0 + lcol, &Bs[r * 64]);
        }
        __syncthreads();
#pragma unroll
        for (int kk = 0; kk < 64; kk += 32) {
            bf16x8 a[4], b[4];
#pragma unroll
            for (int i = 0; i < 4; ++i)
                a[i] = *(const bf16x8*)&As[(wm + i * 16 + l15) * 64 + kk + lq * 8];
#pragma unroll
            for (int i = 0; i < 4; ++i)
                b[i] = *(const bf16x8*)&Bs[(wn + i * 16 + l15) * 64 + kk + lq * 8];
#pragma unroll
            for (int mi = 0; mi < 4; ++mi)
#pragma unroll
                for (int ni = 0; ni < 4; ++ni)
                    acc[mi][ni] = MFMA(a[mi], b[ni], acc[mi][ni]);
        }
        __syncthreads();
    }

#pragma unroll
    for (int mi = 0; mi < 4; ++mi)
#pragma unroll
    for (int ni = 0; ni < 4; ++ni) {
        const int gn = n0 + wn + ni * 16 + l15;
        const float bv = bias ? bias[gn] : 0.f;
#pragma unroll
        for (int i = 0; i < 4; ++i) {
            const int gm = m0 + wm + mi * 16 + lq * 4 + i;
            float v = acc[mi][ni][i] + bv;
            if (GELU) v = 0.5f * v * (1.0f + erff(v * 0.70710678118654752f));
            const size_t off = (size_t)gm * N + gn;
            if (res1) v += res1[off];
            if (res2) v += res2_scale * res2[off];
            if (Yf) Yf[off] = v;
            if (Yb) Yb[off] = (bf16_t)v;
        }
    }
}

// ---------------------------------------------------------------------------
// Small GEMM (adapters, N or K = 192): f32 in, 64x64 tile (R3-proven).
// ---------------------------------------------------------------------------
template<bool GELU>
__global__ __launch_bounds__(256) void gemm_bt(
    const float* __restrict__ X, const float* __restrict__ W,
    const float* __restrict__ bias,
    const float* __restrict__ res1, const float* __restrict__ res2,
    float res2_scale,
    float* __restrict__ Y, int M, int N, int K)
{
    __shared__ bf16_t As[64][72];
    __shared__ bf16_t Bs[64][72];
    const int tid  = threadIdx.x;
    const int n0   = blockIdx.x * 64;
    const int m0   = blockIdx.y * 64;
    const int wave = tid >> 6, lane = tid & 63;
    const int wm   = (wave & 1) * 32, wn = (wave >> 1) * 32;
    const int l15  = lane & 15, lq = lane >> 4;
    f32x4 acc[2][2] = {};
    const int sr = tid >> 4;
    const int sc4 = (tid & 15) * 4;

    for (int k0 = 0; k0 < K; k0 += 64) {
#pragma unroll
        for (int i = 0; i < 4; ++i) {
            const int row = sr + i * 16;
            const float4 xv = *reinterpret_cast<const float4*>(
                X + (size_t)(m0 + row) * K + k0 + sc4);
            bf16x4 p;
            p[0] = (bf16_t)xv.x; p[1] = (bf16_t)xv.y;
            p[2] = (bf16_t)xv.z; p[3] = (bf16_t)xv.w;
            *reinterpret_cast<bf16x4*>(&As[row][sc4]) = p;
        }
#pragma unroll
        for (int i = 0; i < 4; ++i) {
            const int row = sr + i * 16;
            const float4 wv = *reinterpret_cast<const float4*>(
                W + (size_t)(n0 + row) * K + k0 + sc4);
            bf16x4 p;
            p[0] = (bf16_t)wv.x; p[1] = (bf16_t)wv.y;
            p[2] = (bf16_t)wv.z; p[3] = (bf16_t)wv.w;
            *reinterpret_cast<bf16x4*>(&Bs[row][sc4]) = p;
        }
        __syncthreads();
#pragma unroll
        for (int kk = 0; kk < 64; kk += 32) {
            bf16x8 a0 = *reinterpret_cast<const bf16x8*>(&As[wm +      l15][kk + lq * 8]);
            bf16x8 a1 = *reinterpret_cast<const bf16x8*>(&As[wm + 16 + l15][kk + lq * 8]);
            bf16x8 b0 = *reinterpret_cast<const bf16x8*>(&Bs[wn +      l15][kk + lq * 8]);
            bf16x8 b1 = *reinterpret_cast<const bf16x8*>(&Bs[wn + 16 + l15][kk + lq * 8]);
            acc[0][0] = MFMA(a0, b0, acc[0][0]);
            acc[0][1] = MFMA(a0, b1, acc[0][1]);
            acc[1][0] = MFMA(a1, b0, acc[1][0]);
            acc[1][1] = MFMA(a1, b1, acc[1][1]);
        }
        __syncthreads();
    }

#pragma unroll
    for (int mt = 0; mt < 2; ++mt)
#pragma unroll
    for (int nt = 0; nt < 2; ++nt) {
        const int gn = n0 + wn + nt * 16 + l15;
        const float bv = bias[gn];
#pragma unroll
        for (int i = 0; i < 4; ++i) {
            const int gm = m0 + wm + mt * 16 + lq * 4 + i;
            float v = acc[mt][nt][i] + bv;
            if (GELU) v = 0.5f * v * (1.0f + erff(v * 0.70710678118654752f));
            const size_t off = (size_t)gm * N + gn;
            if (res1) v += res1[off];
            if (res2) v += res2_scale * res2[off];
            Y[off] = v;
        }
    }
}

// ---------------------------------------------------------------------------
// MFMA flash attention, bf16 in/out. P reuses Ks LDS; V transposed with
// lanes sweeping keys (2-way banks). LDS ~42KB.
// ---------------------------------------------------------------------------
__global__ __launch_bounds__(256) void flash_k(
    const bf16_t* __restrict__ Q, int ldq,
    const bf16_t* __restrict__ Kp, int ldk,
    const bf16_t* __restrict__ Vp, int ldv,
    bf16_t* __restrict__ O, int ldo,
    int nq, int nk, float scale)
{
    __shared__ bf16_t Qs[64 * 64];
    __shared__ bf16_t Ks[64 * 64];          // doubles as P (stride 64)
    __shared__ bf16_t Vs[64 * 72];          // [dim][key], stride 72 (b128-aligned)
    __shared__ float  sc[64 * 65];
    __shared__ float  mS[64], lS[64], aS[64];

    const int tid = threadIdx.x;
    const int q0 = blockIdx.x * 64, hoff = blockIdx.y * 64, g = blockIdx.z;
    const int wave = tid >> 6, lane = tid & 63;
    const int wm = (wave & 1) * 32, wn = (wave >> 1) * 32;
    const int l15 = lane & 15, lq = lane >> 4;
    const int lrow = lane >> 3, lcol = (lane & 7) * 8;

    // stage Q once (rows clamped)
#pragma unroll
    for (int c = 0; c < 2; ++c) {
        const int r = wave * 16 + c * 8;
        int qrow = q0 + r + lrow; if (qrow > nq - 1) qrow = nq - 1;
        async16(Q + ((size_t)g * nq + qrow) * ldq + hoff + lcol, &Qs[r * 64]);
    }
    if (tid < 64) { mS[tid] = -INFINITY; lS[tid] = 0.f; }
    f32x4 acc[2][2] = {};
    __syncthreads();

    const int vkey = lane;                   // lanes sweep keys
    const int vd0 = wave * 16;               // wave's 16-dim slice

    for (int kk0 = 0; kk0 < nk; kk0 += 64) {
        // stage K (async) and V (transposed, conflict-free stores)
#pragma unroll
        for (int c = 0; c < 2; ++c) {
            const int r = wave * 16 + c * 8;
            int krow = kk0 + r + lrow; if (krow > nk - 1) krow = nk - 1;
            async16(Kp + ((size_t)g * nk + krow) * ldk + hoff + lcol, &Ks[r * 64]);
        }
        {
            int key = kk0 + vkey; if (key > nk - 1) key = nk - 1;
            const bf16_t* vp = Vp + ((size_t)g * nk + key) * ldv + hoff + vd0;
            bf16x8 v0 = *(const bf16x8*)vp;
            bf16x8 v1 = *(const bf16x8*)(vp + 8);
#pragma unroll
            for (int j = 0; j < 8; ++j) Vs[(vd0 + j) * 72 + vkey] = v0[j];
#pragma unroll
            for (int j = 0; j < 8; ++j) Vs[(vd0 + 8 + j) * 72 + vkey] = v1[j];
        }
        __syncthreads();

        // S = Q K^T (scaled on write to sc)
        f32x4 s[2][2] = {};
#pragma unroll
        for (int kk = 0; kk < 64; kk += 32) {
            bf16x8 a0 = *(const bf16x8*)&Qs[(wm +      l15) * 64 + kk + lq * 8];
            bf16x8 a1 = *(const bf16x8*)&Qs[(wm + 16 + l15) * 64 + kk + lq * 8];
            bf16x8 b0 = *(const bf16x8*)&Ks[(wn +      l15) * 64 + kk + lq * 8];
            bf16x8 b1 = *(const bf16x8*)&Ks[(wn + 16 + l15) * 64 + kk + lq * 8];
            s[0][0] = MFMA(a0, b0, s[0][0]);
            s[0][1] = MFMA(a0, b1, s[0][1]);
            s[1][0] = MFMA(a1, b0, s[1][0]);
            s[1][1] = MFMA(a1, b1, s[1][1]);
        }
#pragma unroll
        for (int mt = 0; mt < 2; ++mt)
#pragma unroll
        for (int nt = 0; nt < 2; ++nt)
#pragma unroll
        for (int i = 0; i < 4; ++i)
            sc[(wm + mt * 16 + lq * 4 + i) * 65 + wn + nt * 16 + l15] = s[mt][nt][i] * scale;
        __syncthreads();

        // online softmax: 4 same-wave threads per row, 16 cols each
        {
            const int row = tid >> 2, c0 = (tid & 3) * 16;
            float pv[16];
            float lmax = -INFINITY;
#pragma unroll
            for (int c2 = 0; c2 < 16; ++c2) {
                float v = (kk0 + c0 + c2 < nk) ? sc[row * 65 + c0 + c2] : -INFINITY;
                pv[c2] = v;
                lmax = fmaxf(lmax, v);
            }
            lmax = fmaxf(lmax, __shfl_xor(lmax, 1));
            lmax = fmaxf(lmax, __shfl_xor(lmax, 2));
            const float mold = mS[row];
            const float mnew = fmaxf(mold, lmax);
            const float alpha = expf(mold - mnew);
            float psum = 0.f;
            bf16x8 p0, p1;
#pragma unroll
            for (int c2 = 0; c2 < 16; ++c2) {
                const float e = (pv[c2] == -INFINITY) ? 0.f : expf(pv[c2] - mnew);
                psum += e;
                if (c2 < 8) p0[c2] = (bf16_t)e; else p1[c2 - 8] = (bf16_t)e;
            }
            psum += __shfl_xor(psum, 1);
            psum += __shfl_xor(psum, 2);
            *(bf16x8*)&Ks[row * 64 + c0]     = p0;   // P into dead K tile
            *(bf16x8*)&Ks[row * 64 + c0 + 8] = p1;
            const float lnew = lS[row] * alpha + psum;  // 4 lanes: same value
            mS[row] = mnew; lS[row] = lnew; aS[row] = alpha;
        }
        __syncthreads();

        // O = O*alpha + P*V
#pragma unroll
        for (int mt = 0; mt < 2; ++mt)
#pragma unroll
        for (int i = 0; i < 4; ++i) {
            const float a = aS[wm + mt * 16 + lq * 4 + i];
            acc[mt][0][i] *= a;
            acc[mt][1][i] *= a;
        }
#pragma unroll
        for (int kk = 0; kk < 64; kk += 32) {
            bf16x8 a0 = *(const bf16x8*)&Ks[(wm +      l15) * 64 + kk + lq * 8];
            bf16x8 a1 = *(const bf16x8*)&Ks[(wm + 16 + l15) * 64 + kk + lq * 8];
            bf16x8 b0 = *(const bf16x8*)&Vs[(wn +      l15) * 72 + kk + lq * 8];
            bf16x8 b1 = *(const bf16x8*)&Vs[(wn + 16 + l15) * 72 + kk + lq * 8];
            acc[0][0] = MFMA(a0, b0, acc[0][0]);
            acc[0][1] = MFMA(a0, b1, acc[0][1]);
            acc[1][0] = MFMA(a1, b0, acc[1][0]);
            acc[1][1] = MFMA(a1, b1, acc[1][1]);
        }
        __syncthreads();
    }

#pragma unroll
    for (int mt = 0; mt < 2; ++mt)
#pragma unroll
    for (int nt = 0; nt < 2; ++nt) {
        const int col = wn + nt * 16 + l15;
#pragma unroll
        for (int i = 0; i < 4; ++i) {
            const int r = wm + mt * 16 + lq * 4 + i;
            const int qrow = q0 + r;
            if (qrow < nq)
                O[((size_t)g * nq + qrow) * ldo + hoff + col] = (bf16_t)(acc[mt][nt][i] / lS[r]);
        }
    }
}

// ---------------------------------------------------------------------------
// Scalar attention for T2S (nk=8), bf16 in/out.
// ---------------------------------------------------------------------------
__global__ __launch_bounds__(256) void attn_k(
    const bf16_t* __restrict__ Q, int ldq,
    const bf16_t* __restrict__ Kp, int ldk,
    const bf16_t* __restrict__ Vp, int ldv,
    bf16_t* __restrict__ O, int ldo,
    int nq, int nk, float scale)
{
    __shared__ float sc[64];
    __shared__ float qv[64];
    __shared__ float red[256];
    __shared__ float s_inv;
    const int tid = threadIdx.x;
    const int bx  = blockIdx.x;
    const int qi  = bx % nq;
    const int t1  = bx / nq;
    const int h   = t1 % 12;
    const int b   = t1 / 12;
    const int hoff = h * 64;
    const size_t qrow = (size_t)b * nq + qi;
    if (tid < 64) qv[tid] = (float)Q[qrow * ldq + hoff + tid];
    __syncthreads();

    const int wave = tid >> 6, lane = tid & 63;
    const size_t kbase = (size_t)b * nk;
    for (int j = wave; j < nk; j += 4) {
        float p = (float)Kp[(kbase + j) * ldk + hoff + lane] * qv[lane];
#pragma unroll
        for (int off = 32; off > 0; off >>= 1) p += __shfl_xor(p, off);
        if (lane == 0) sc[j] = p * scale;
    }
    __syncthreads();

    float lm = -INFINITY;
    for (int j = tid; j < nk; j += 256) lm = fmaxf(lm, sc[j]);
    red[tid] = lm; __syncthreads();
    for (int s = 128; s > 0; s >>= 1) {
        if (tid < s) red[tid] = fmaxf(red[tid], red[tid + s]);
        __syncthreads();
    }
    const float mx = red[0];
    __syncthreads();
    float ls = 0.f;
    for (int j = tid; j < nk; j += 256) { float e = expf(sc[j] - mx); sc[j] = e; ls += e; }
    red[tid] = ls; __syncthreads();
    for (int s = 128; s > 0; s >>= 1) {
        if (tid < s) red[tid] += red[tid + s];
        __syncthreads();
    }
    if (tid == 0) s_inv = 1.0f / red[0];
    __syncthreads();

    const int d = tid & 63, slice = tid >> 6;
    float acc = 0.f;
    for (int j = slice; j < nk; j += 4)
        acc += sc[j] * (float)Vp[(kbase + j) * ldv + hoff + d];
    red[tid] = acc; __syncthreads();
    if (tid < 64) {
        float o = (red[tid] + red[tid + 64] + red[tid + 128] + red[tid + 192]) * s_inv;
        O[qrow * ldo + hoff + tid] = (bf16_t)o;
    }
}

// ---------------------------------------------------------------------------
// LayerNorm(768): bf16 out always, f32 out optional.
// ---------------------------------------------------------------------------
__global__ __launch_bounds__(256) void ln_k(
    const float* __restrict__ x,
    const float* __restrict__ g, const float* __restrict__ bta,
    float* __restrict__ yf, bf16_t* __restrict__ yb)
{
    __shared__ float red[256], red2[256];
    __shared__ float s_m, s_r;
    const int row = blockIdx.x, tid = threadIdx.x;
    const size_t base = (size_t)row * 768;
    const float v0 = x[base + tid];
    const float v1 = x[base + tid + 256];
    const float v2 = x[base + tid + 512];
    red[tid]  = v0 + v1 + v2;
    red2[tid] = v0 * v0 + v1 * v1 + v2 * v2;
    __syncthreads();
    for (int st = 128; st > 0; st >>= 1) {
        if (tid < st) { red[tid] += red[tid + st]; red2[tid] += red2[tid + st]; }
        __syncthreads();
    }
    if (tid == 0) {
        const float m = red[0] * (1.f / 768.f);
        const float var = red2[0] * (1.f / 768.f) - m * m;
        s_m = m; s_r = rsqrtf(var + 1e-5f);
    }
    __syncthreads();
    const float m = s_m, r = s_r;
    const float o0 = (v0 - m) * r * g[tid]       + bta[tid];
    const float o1 = (v1 - m) * r * g[tid + 256] + bta[tid + 256];
    const float o2 = (v2 - m) * r * g[tid + 512] + bta[tid + 512];
    yb[base + tid]       = (bf16_t)o0;
    yb[base + tid + 256] = (bf16_t)o1;
    yb[base + tid + 512] = (bf16_t)o2;
    if (yf) {
        yf[base + tid]       = o0;
        yf[base + tid + 256] = o1;
        yf[base + tid + 512] = o2;
    }
}

// --------------------------- elementwise helpers ---------------------------
__global__ void addpos_k(const float* __restrict__ src, const float* __restrict__ pos,
                         bf16_t* __restrict__ dst, int nrep) {
    const int row = blockIdx.x, tid = threadIdx.x;
    const size_t base = (size_t)row * 768;
    const size_t pbase = (size_t)(row % nrep) * 768;
    for (int k = 0; k < 3; ++k) {
        int c = tid + k * 256;
        dst[base + c] = (bf16_t)(src[base + c] + pos[pbase + c]);
    }
}
__global__ void t2s_prep_q(const float* __restrict__ sx, const float* __restrict__ pos,
                           bf16_t* __restrict__ dst) {
    const int row = blockIdx.x, tid = threadIdx.x;
    const int t = row & 7, bn = row >> 3, n = bn % 196, b = bn / 196;
    const size_t src = (size_t)((b * 8 + t) * 196 + n) * 768;
    const size_t dbase = (size_t)row * 768;
    const size_t pbase = (size_t)t * 768;
    for (int k = 0; k < 3; ++k) {
        int c = tid + k * 256;
        dst[dbase + c] = (bf16_t)(sx[src + c] + pos[pbase + c]);
    }
}
__global__ void t2s_prep_kv(const float* __restrict__ tcur, const float* __restrict__ pos,
                            bf16_t* __restrict__ dst) {
    const int row = blockIdx.x, tid = threadIdx.x;
    const int t = row & 7, bn = row >> 3, n = bn % 196, b = bn / 196;
    const size_t src = (size_t)(b * 1568 + t * 196 + n) * 768;
    const size_t dbase = (size_t)row * 768;
    const size_t pbase = (size_t)t * 768;
    for (int k = 0; k < 3; ++k) {
        int c = tid + k * 256;
        dst[dbase + c] = (bf16_t)(tcur[src + c] + pos[pbase + c]);
    }
}
__global__ void s_out_k(const float* __restrict__ sx, const float* __restrict__ o,
                        float* __restrict__ out) {
    const int row = blockIdx.x, tid = threadIdx.x;
    const int n = row % 196, bt = row / 196, t = bt & 7, b = bt >> 3;
    const size_t obase = (size_t)((b * 196 + n) * 8 + t) * 768;
    const size_t base = (size_t)row * 768;
    for (int k = 0; k < 3; ++k) {
        int c = tid + k * 256;
        out[base + c] = sx[base + c] + o[obase + c];
    }
}
__global__ void build_qkv_bias(const float* __restrict__ qb,
                               const float* __restrict__ vb,
                               float* __restrict__ dst) {
    int i = blockIdx.x * 256 + threadIdx.x;
    if (i < 768) dst[i] = qb[i];
    else if (i < 1536) dst[i] = 0.f;
    else if (i < 2304) dst[i] = vb[i - 1536];
}

// Weight convert: 10 f32 weights -> one bf16 arena (float4 granularity).
// cum[i] = OFF_i / 4 (arena offset in float4 units). R5: fixed table.
struct WPtrs { const float* p[10]; };
__global__ void wcvt(WPtrs s, bf16_t* __restrict__ dst) {
    const int cum[11] = {0, 442368, 589824, 737280, 1032192, 1179648,
                         1327104, 1622016, 1769472, 2359296, 2949120};
    const int gi = blockIdx.x * 256 + threadIdx.x;
    int seg = 0;
#pragma unroll
    for (int i = 1; i < 10; ++i) if (gi >= cum[i]) seg = i;
    const float4 v = ((const float4*)s.p[seg])[gi - cum[seg]];
    bf16x4 o;
    o[0] = (bf16_t)v.x; o[1] = (bf16_t)v.y; o[2] = (bf16_t)v.z; o[3] = (bf16_t)v.w;
    ((bf16x4*)dst)[gi] = o;
}

// Arena offsets (elements)
#define OFF_QKV    0
#define OFF_APROJ  1769472
#define OFF_S2TQ   2359296
#define OFF_S2TKV  2949120
#define OFF_S2TP   4128768
#define OFF_T2SQ   4718592
#define OFF_T2SKV  5308416
#define OFF_T2SP   6488064
#define OFF_FC1    7077888
#define OFF_FC2    9437184
#define W_TOTAL    11796480

// ---------------------------------------------------------------------------
extern "C" void kernel_launch(void* const* d_in, const int* in_sizes, int n_in,
                              void* d_out, int out_size, void* d_ws, size_t ws_size,
                              hipStream_t stream)
{
    typedef const float* fp;
    fp s_x     = (fp)d_in[0];
    fp t_x     = (fp)d_in[1];
    fp g1      = (fp)d_in[2];
    fp bb1     = (fp)d_in[3];
    fp qkv_w   = (fp)d_in[4];
    fp q_bias  = (fp)d_in[5];
    fp v_bias  = (fp)d_in[6];
    fp aproj_w = (fp)d_in[7];
    fp aproj_b = (fp)d_in[8];
    fp sa_w1   = (fp)d_in[9];
    fp sa_b1   = (fp)d_in[10];
    fp sa_w2   = (fp)d_in[11];
    fp sa_b2   = (fp)d_in[12];
    fp s2t_pos_cnn  = (fp)d_in[13];
    fp s2t_pos_vmae = (fp)d_in[14];
    fp s2t_qw  = (fp)d_in[15];
    fp s2t_qb  = (fp)d_in[16];
    fp s2t_kvw = (fp)d_in[17];
    fp s2t_kvb = (fp)d_in[18];
    fp s2t_pw  = (fp)d_in[19];
    fp s2t_pb  = (fp)d_in[20];
    fp t2s_pos_cnn  = (fp)d_in[21];
    fp t2s_pos_vmae = (fp)d_in[22];
    fp t2s_qw  = (fp)d_in[23];
    fp t2s_qb  = (fp)d_in[24];
    fp t2s_kvw = (fp)d_in[25];
    fp t2s_kvb = (fp)d_in[26];
    fp t2s_pw  = (fp)d_in[27];
    fp t2s_pb  = (fp)d_in[28];
    fp g2      = (fp)d_in[29];
    fp bb2     = (fp)d_in[30];
    fp fc1_w   = (fp)d_in[31];
    fp fc1_b   = (fp)d_in[32];
    fp fc2_w   = (fp)d_in[33];
    fp fc2_b   = (fp)d_in[34];
    fp ma_w1   = (fp)d_in[35];
    fp ma_b1   = (fp)d_in[36];
    fp ma_w2   = (fp)d_in[37];
    fp ma_b2   = (fp)d_in[38];

    const size_t RD = (size_t)6272 * 768;

    float* ws   = (float*)d_ws;
    float* F    = ws;                      // aproj out / mad out
    float* G    = F + RD;                  // running t
    float* CI   = G + RD;                  // t2s_p out -> ln2 f32 out
    float* Hb   = CI + RD;                 // 6272x192 adapter hidden
    float* qkvb = Hb + (size_t)6272 * 192;
    bf16_t* BW  = (bf16_t*)(qkvb + 2304);  // weight arena
    bf16_t* Xb  = BW + W_TOTAL;            // GEMM A-input staging (RD)
    bf16_t* Eb  = Xb + RD;                 // q mirrors / flash out (RD)
    bf16_t* Fb  = Eb + RD;                 // flash/attn out (RD)
    bf16_t* MB  = Fb + RD;                 // big mirror: qkv/kv/fc1 (6272x3072)

    float* out_s = (float*)d_out;          // [32*196, 768]
    float* out_t = out_s + RD;             // [4*1568, 768]

    const dim3 blk(256);

    // ---- weight conversion (all big-GEMM weights -> bf16 arena) ----
    WPtrs wp;
    wp.p[0] = qkv_w;  wp.p[1] = aproj_w; wp.p[2] = s2t_qw; wp.p[3] = s2t_kvw;
    wp.p[4] = s2t_pw; wp.p[5] = t2s_qw;  wp.p[6] = t2s_kvw; wp.p[7] = t2s_pw;
    wp.p[8] = fc1_w;  wp.p[9] = fc2_w;
    wcvt<<<11520, blk, 0, stream>>>(wp, BW);

    // ---- stage 1: self-attention + serial adapter ----
    ln_k<<<6272, blk, 0, stream>>>(t_x, g1, bb1, nullptr, Xb);
    build_qkv_bias<<<9, blk, 0, stream>>>(q_bias, v_bias, qkvb);
    gemm128<false><<<dim3(18, 49), blk, 0, stream>>>(
        Xb, BW + OFF_QKV, qkvb, nullptr, nullptr, 0.f, nullptr, MB, 6272, 2304, 768);
    flash_k<<<dim3(25, 12, 4), blk, 0, stream>>>(
        MB, 2304, MB + 768, 2304, MB + 1536, 2304, Eb, 768, 1568, 1568, 0.125f);
    gemm128<false><<<dim3(6, 49), blk, 0, stream>>>(
        Eb, BW + OFF_APROJ, aproj_b, nullptr, nullptr, 0.f, F, nullptr, 6272, 768, 768);
    gemm_bt<true><<<dim3(3, 98), blk, 0, stream>>>(
        F, sa_w1, sa_b1, nullptr, nullptr, 0.f, Hb, 6272, 192, 768);
    gemm_bt<false><<<dim3(12, 98), blk, 0, stream>>>(
        Hb, sa_w2, sa_b2, F, t_x, 1.0f, G, 6272, 768, 192);   // t1

    // ---- stage 2: S2T cross-attn ----
    addpos_k<<<6272, blk, 0, stream>>>(G, s2t_pos_vmae, Xb, 196);
    gemm128<false><<<dim3(6, 49), blk, 0, stream>>>(
        Xb, BW + OFF_S2TQ, s2t_qb, nullptr, nullptr, 0.f, nullptr, Eb, 6272, 768, 768);
    addpos_k<<<6272, blk, 0, stream>>>(s_x, s2t_pos_cnn, Xb, 196);
    gemm128<false><<<dim3(12, 49), blk, 0, stream>>>(
        Xb, BW + OFF_S2TKV, s2t_kvb, nullptr, nullptr, 0.f, nullptr, MB, 6272, 1536, 768);
    flash_k<<<dim3(4, 12, 32), blk, 0, stream>>>(
        Eb, 768, MB, 1536, MB + 768, 1536, Fb, 768, 196, 196, 0.125f);
    gemm128<false><<<dim3(6, 49), blk, 0, stream>>>(
        Fb, BW + OFF_S2TP, s2t_pb, G, nullptr, 0.f, G, nullptr, 6272, 768, 768);  // t2

    // ---- stage 3: T2S cross-attn ----
    t2s_prep_q<<<6272, blk, 0, stream>>>(s_x, t2s_pos_cnn, Xb);
    gemm128<false><<<dim3(6, 49), blk, 0, stream>>>(
        Xb, BW + OFF_T2SQ, t2s_qb, nullptr, nullptr, 0.f, nullptr, Eb, 6272, 768, 768);
    t2s_prep_kv<<<6272, blk, 0, stream>>>(G, t2s_pos_vmae, Xb);
    gemm128<false><<<dim3(12, 49), blk, 0, stream>>>(
        Xb, BW + OFF_T2SKV, t2s_kvb, nullptr, nullptr, 0.f, nullptr, MB, 6272, 1536, 768);
    attn_k<<<784 * 12 * 8, blk, 0, stream>>>(
        Eb, 768, MB, 1536, MB + 768, 1536, Fb, 768, 8, 8, 0.125f);
    gemm128<false><<<dim3(6, 49), blk, 0, stream>>>(
        Fb, BW + OFF_T2SP, t2s_pb, nullptr, nullptr, 0.f, CI, nullptr, 6272, 768, 768);
    s_out_k<<<6272, blk, 0, stream>>>(s_x, CI, out_s);

    // ---- stage 4: MLP + parallel adapter ----
    ln_k<<<6272, blk, 0, stream>>>(G, g2, bb2, CI, Xb);
    gemm128<true><<<dim3(24, 49), blk, 0, stream>>>(
        Xb, BW + OFF_FC1, fc1_b, nullptr, nullptr, 0.f, nullptr, MB, 6272, 3072, 768);
    gemm_bt<true><<<dim3(3, 98), blk, 0, stream>>>(
        CI, ma_w1, ma_b1, nullptr, nullptr, 0.f, Hb, 6272, 192, 768);
    gemm_bt<false><<<dim3(12, 98), blk, 0, stream>>>(
        Hb, ma_w2, ma_b2, nullptr, nullptr, 0.f, F, 6272, 768, 192);
    gemm128<false><<<dim3(6, 49), blk, 0, stream>>>(
        MB, BW + OFF_FC2, fc2_b, G, F, 0.5f, out_t, nullptr, 6272, 768, 3072);
}

// Round 6
// 1180.967 us; speedup vs baseline: 9.9983x; 1.0394x over previous
//
#include <hip/hip_runtime.h>
#include <hip/hip_bf16.h>
#include <math.h>

// ---------------------------------------------------------------------------
// Block_38543036514772 on MI355X (gfx950). f32 in/out; bf16 MFMA internals.
// R6: flash rewritten — wave-owns-16-rows, in-register online softmax (no sc
// LDS array), stride-68 padded LDS (2-way P stores, 8-way-floor b128 reads),
// P aliases Ks, 3 barriers/iter, 25.5KB LDS. N=768 GEMMs get a 128x64 tile
// (588 blocks vs 294 -> fixes 1-block/CU underoccupancy).
// ---------------------------------------------------------------------------

typedef __bf16 bf16_t;
typedef bf16_t bf16x4 __attribute__((ext_vector_type(4)));
typedef bf16_t bf16x8 __attribute__((ext_vector_type(8)));
typedef float  f32x4  __attribute__((ext_vector_type(4)));

typedef const __attribute__((address_space(1))) void* gas_t;
typedef __attribute__((address_space(3))) void* las_t;
__device__ __forceinline__ void async16(const void* g, void* l) {
    // LDS dest = wave-uniform base + lane*16 (no padding allowed!)
    __builtin_amdgcn_global_load_lds((gas_t)g, (las_t)l, 16, 0, 0);
}

#define MFMA(a,b,c) __builtin_amdgcn_mfma_f32_16x16x32_bf16((a),(b),(c),0,0,0)

// ---------------------------------------------------------------------------
// Big GEMM 128x128: Y = act(A[M,K]bf16 * W[N,K]bf16^T + bias) (+res1)(+s*res2)
// ---------------------------------------------------------------------------
template<bool GELU>
__global__ __launch_bounds__(256) void gemm128(
    const bf16_t* __restrict__ A, const bf16_t* __restrict__ W,
    const float* __restrict__ bias,
    const float* __restrict__ res1, const float* __restrict__ res2,
    float res2_scale,
    float* __restrict__ Yf, bf16_t* __restrict__ Yb,
    int M, int N, int K)
{
    __shared__ bf16_t As[128*64];
    __shared__ bf16_t Bs[128*64];
    const int tid = threadIdx.x, wave = tid >> 6, lane = tid & 63;
    const int m0 = blockIdx.y * 128, n0 = blockIdx.x * 128;
    const int wm = (wave & 1) * 64, wn = (wave >> 1) * 64;
    const int l15 = lane & 15, lq = lane >> 4;
    const int lrow = lane >> 3, lcol = (lane & 7) * 8;

    f32x4 acc[4][4] = {};

    for (int k0 = 0; k0 < K; k0 += 64) {
#pragma unroll
        for (int c = 0; c < 4; ++c) {
            const int r = wave * 32 + c * 8;
            async16(A + (size_t)(m0 + r + lrow) * K + k0 + lcol, &As[r * 64]);
            async16(W + (size_t)(n0 + r + lrow) * K + k0 + lcol, &Bs[r * 64]);
        }
        __syncthreads();
#pragma unroll
        for (int kk = 0; kk < 64; kk += 32) {
            bf16x8 a[4], b[4];
#pragma unroll
            for (int i = 0; i < 4; ++i)
                a[i] = *(const bf16x8*)&As[(wm + i * 16 + l15) * 64 + kk + lq * 8];
#pragma unroll
            for (int i = 0; i < 4; ++i)
                b[i] = *(const bf16x8*)&Bs[(wn + i * 16 + l15) * 64 + kk + lq * 8];
#pragma unroll
            for (int mi = 0; mi < 4; ++mi)
#pragma unroll
                for (int ni = 0; ni < 4; ++ni)
                    acc[mi][ni] = MFMA(a[mi], b[ni], acc[mi][ni]);
        }
        __syncthreads();
    }

#pragma unroll
    for (int mi = 0; mi < 4; ++mi)
#pragma unroll
    for (int ni = 0; ni < 4; ++ni) {
        const int gn = n0 + wn + ni * 16 + l15;
        const float bv = bias ? bias[gn] : 0.f;
#pragma unroll
        for (int i = 0; i < 4; ++i) {
            const int gm = m0 + wm + mi * 16 + lq * 4 + i;
            float v = acc[mi][ni][i] + bv;
            if (GELU) v = 0.5f * v * (1.0f + erff(v * 0.70710678118654752f));
            const size_t off = (size_t)gm * N + gn;
            if (res1) v += res1[off];
            if (res2) v += res2_scale * res2[off];
            if (Yf) Yf[off] = v;
            if (Yb) Yb[off] = (bf16_t)v;
        }
    }
}

// ---------------------------------------------------------------------------
// GEMM 128x64 tile for N=768 layers: 2x more blocks -> fixes 1.15-block/CU.
// Wave tile 64x32 (acc[4][2]), LDS 24KB.
// ---------------------------------------------------------------------------
template<bool GELU>
__global__ __launch_bounds__(256) void gemm128x64(
    const bf16_t* __restrict__ A, const bf16_t* __restrict__ W,
    const float* __restrict__ bias,
    const float* __restrict__ res1, const float* __restrict__ res2,
    float res2_scale,
    float* __restrict__ Yf, bf16_t* __restrict__ Yb,
    int M, int N, int K)
{
    __shared__ bf16_t As[128*64];
    __shared__ bf16_t Bs[64*64];
    const int tid = threadIdx.x, wave = tid >> 6, lane = tid & 63;
    const int m0 = blockIdx.y * 128, n0 = blockIdx.x * 64;
    const int wm = (wave & 1) * 64, wn = (wave >> 1) * 32;
    const int l15 = lane & 15, lq = lane >> 4;
    const int lrow = lane >> 3, lcol = (lane & 7) * 8;

    f32x4 acc[4][2] = {};

    for (int k0 = 0; k0 < K; k0 += 64) {
#pragma unroll
        for (int c = 0; c < 4; ++c) {
            const int r = wave * 32 + c * 8;
            async16(A + (size_t)(m0 + r + lrow) * K + k0 + lcol, &As[r * 64]);
        }
#pragma unroll
        for (int c = 0; c < 2; ++c) {
            const int r = wave * 16 + c * 8;
            async16(W + (size_t)(n0 + r + lrow) * K + k0 + lcol, &Bs[r * 64]);
        }
        __syncthreads();
#pragma unroll
        for (int kk = 0; kk < 64; kk += 32) {
            bf16x8 a[4], b[2];
#pragma unroll
            for (int i = 0; i < 4; ++i)
                a[i] = *(const bf16x8*)&As[(wm + i * 16 + l15) * 64 + kk + lq * 8];
#pragma unroll
            for (int i = 0; i < 2; ++i)
                b[i] = *(const bf16x8*)&Bs[(wn + i * 16 + l15) * 64 + kk + lq * 8];
#pragma unroll
            for (int mi = 0; mi < 4; ++mi)
#pragma unroll
                for (int ni = 0; ni < 2; ++ni)
                    acc[mi][ni] = MFMA(a[mi], b[ni], acc[mi][ni]);
        }
        __syncthreads();
    }

#pragma unroll
    for (int mi = 0; mi < 4; ++mi)
#pragma unroll
    for (int ni = 0; ni < 2; ++ni) {
        const int gn = n0 + wn + ni * 16 + l15;
        const float bv = bias ? bias[gn] : 0.f;
#pragma unroll
        for (int i = 0; i < 4; ++i) {
            const int gm = m0 + wm + mi * 16 + lq * 4 + i;
            float v = acc[mi][ni][i] + bv;
            if (GELU) v = 0.5f * v * (1.0f + erff(v * 0.70710678118654752f));
            const size_t off = (size_t)gm * N + gn;
            if (res1) v += res1[off];
            if (res2) v += res2_scale * res2[off];
            if (Yf) Yf[off] = v;
            if (Yb) Yb[off] = (bf16_t)v;
        }
    }
}

// ---------------------------------------------------------------------------
// Small GEMM (adapters, N or K = 192): f32 in, 64x64 tile.
// ---------------------------------------------------------------------------
template<bool GELU>
__global__ __launch_bounds__(256) void gemm_bt(
    const float* __restrict__ X, const float* __restrict__ W,
    const float* __restrict__ bias,
    const float* __restrict__ res1, const float* __restrict__ res2,
    float res2_scale,
    float* __restrict__ Y, int M, int N, int K)
{
    __shared__ bf16_t As[64][72];
    __shared__ bf16_t Bs[64][72];
    const int tid  = threadIdx.x;
    const int n0   = blockIdx.x * 64;
    const int m0   = blockIdx.y * 64;
    const int wave = tid >> 6, lane = tid & 63;
    const int wm   = (wave & 1) * 32, wn = (wave >> 1) * 32;
    const int l15  = lane & 15, lq = lane >> 4;
    f32x4 acc[2][2] = {};
    const int sr = tid >> 4;
    const int sc4 = (tid & 15) * 4;

    for (int k0 = 0; k0 < K; k0 += 64) {
#pragma unroll
        for (int i = 0; i < 4; ++i) {
            const int row = sr + i * 16;
            const float4 xv = *reinterpret_cast<const float4*>(
                X + (size_t)(m0 + row) * K + k0 + sc4);
            bf16x4 p;
            p[0] = (bf16_t)xv.x; p[1] = (bf16_t)xv.y;
            p[2] = (bf16_t)xv.z; p[3] = (bf16_t)xv.w;
            *reinterpret_cast<bf16x4*>(&As[row][sc4]) = p;
        }
#pragma unroll
        for (int i = 0; i < 4; ++i) {
            const int row = sr + i * 16;
            const float4 wv = *reinterpret_cast<const float4*>(
                W + (size_t)(n0 + row) * K + k0 + sc4);
            bf16x4 p;
            p[0] = (bf16_t)wv.x; p[1] = (bf16_t)wv.y;
            p[2] = (bf16_t)wv.z; p[3] = (bf16_t)wv.w;
            *reinterpret_cast<bf16x4*>(&Bs[row][sc4]) = p;
        }
        __syncthreads();
#pragma unroll
        for (int kk = 0; kk < 64; kk += 32) {
            bf16x8 a0 = *reinterpret_cast<const bf16x8*>(&As[wm +      l15][kk + lq * 8]);
            bf16x8 a1 = *reinterpret_cast<const bf16x8*>(&As[wm + 16 + l15][kk + lq * 8]);
            bf16x8 b0 = *reinterpret_cast<const bf16x8*>(&Bs[wn +      l15][kk + lq * 8]);
            bf16x8 b1 = *reinterpret_cast<const bf16x8*>(&Bs[wn + 16 + l15][kk + lq * 8]);
            acc[0][0] = MFMA(a0, b0, acc[0][0]);
            acc[0][1] = MFMA(a0, b1, acc[0][1]);
            acc[1][0] = MFMA(a1, b0, acc[1][0]);
            acc[1][1] = MFMA(a1, b1, acc[1][1]);
        }
        __syncthreads();
    }

#pragma unroll
    for (int mt = 0; mt < 2; ++mt)
#pragma unroll
    for (int nt = 0; nt < 2; ++nt) {
        const int gn = n0 + wn + nt * 16 + l15;
        const float bv = bias[gn];
#pragma unroll
        for (int i = 0; i < 4; ++i) {
            const int gm = m0 + wm + mt * 16 + lq * 4 + i;
            float v = acc[mt][nt][i] + bv;
            if (GELU) v = 0.5f * v * (1.0f + erff(v * 0.70710678118654752f));
            const size_t off = (size_t)gm * N + gn;
            if (res1) v += res1[off];
            if (res2) v += res2_scale * res2[off];
            Y[off] = v;
        }
    }
}

// ---------------------------------------------------------------------------
// Flash attention v2: wave w owns Q rows [16w,16w+16) x all 64 cols.
// In-register online softmax (m/l/alpha in VGPRs, shfl_xor over l15).
// All LDS stride 68 bf16 (136B = 8 mod 128 bank bytes): P scalar stores
// 2-way (free), b128 frag reads at the 8-way floor. P aliases Ks.
// ---------------------------------------------------------------------------
__global__ __launch_bounds__(256) void flash_k(
    const bf16_t* __restrict__ Q, int ldq,
    const bf16_t* __restrict__ Kp, int ldk,
    const bf16_t* __restrict__ Vp, int ldv,
    bf16_t* __restrict__ O, int ldo,
    int nq, int nk, float scale)
{
    __shared__ bf16_t Qs[64 * 68];
    __shared__ bf16_t Ks[64 * 68];    // aliased by P after the QK barrier
    __shared__ bf16_t Vs[64 * 68];    // [dim][key]

    const int tid = threadIdx.x, wave = tid >> 6, lane = tid & 63;
    const int q0 = blockIdx.x * 64, hoff = blockIdx.y * 64, g = blockIdx.z;
    const int l15 = lane & 15, lq = lane >> 4;
    const int wm16 = wave * 16;
    const int sr = tid >> 3, sc8 = (tid & 7) * 8;   // staging: 32 rows x 8 col-chunks

    // ---- stage Q once (rows clamped) ----
    {
        int r0 = q0 + sr;      if (r0 > nq - 1) r0 = nq - 1;
        int r1 = q0 + sr + 32; if (r1 > nq - 1) r1 = nq - 1;
        bf16x8 a = *(const bf16x8*)(Q + ((size_t)g * nq + r0) * ldq + hoff + sc8);
        bf16x8 b = *(const bf16x8*)(Q + ((size_t)g * nq + r1) * ldq + hoff + sc8);
        *(bf16x8*)&Qs[sr * 68 + sc8] = a;
        *(bf16x8*)&Qs[(sr + 32) * 68 + sc8] = b;
    }
    float mrow[4], lrow[4];
#pragma unroll
    for (int i = 0; i < 4; ++i) { mrow[i] = -INFINITY; lrow[i] = 0.f; }
    f32x4 acc[4] = {};   // O rows lq*4+i (wave strip), cols nt*16+l15

    for (int kk0 = 0; kk0 < nk; kk0 += 64) {
        __syncthreads();   // prev-iter PV reads done (and Q visible at iter 0)
        // ---- stage K rows + V transposed ----
        {
            int r0 = kk0 + sr;      if (r0 > nk - 1) r0 = nk - 1;
            int r1 = kk0 + sr + 32; if (r1 > nk - 1) r1 = nk - 1;
            bf16x8 a = *(const bf16x8*)(Kp + ((size_t)g * nk + r0) * ldk + hoff + sc8);
            bf16x8 b = *(const bf16x8*)(Kp + ((size_t)g * nk + r1) * ldk + hoff + sc8);
            *(bf16x8*)&Ks[sr * 68 + sc8] = a;
            *(bf16x8*)&Ks[(sr + 32) * 68 + sc8] = b;
            int key = kk0 + lane; if (key > nk - 1) key = nk - 1;
            const bf16_t* vp = Vp + ((size_t)g * nk + key) * ldv + hoff + wm16;
            bf16x8 v0 = *(const bf16x8*)vp;
            bf16x8 v1 = *(const bf16x8*)(vp + 8);
#pragma unroll
            for (int j = 0; j < 8; ++j) Vs[(wm16 + j) * 68 + lane] = v0[j];
#pragma unroll
            for (int j = 0; j < 8; ++j) Vs[(wm16 + 8 + j) * 68 + lane] = v1[j];
        }
        __syncthreads();   // staging visible

        // ---- S = Q K^T : 16 rows (own strip) x 64 cols ----
        f32x4 s[4] = {};
#pragma unroll
        for (int kk = 0; kk < 64; kk += 32) {
            bf16x8 a = *(const bf16x8*)&Qs[(wm16 + l15) * 68 + kk + lq * 8];
#pragma unroll
            for (int nt = 0; nt < 4; ++nt) {
                bf16x8 b = *(const bf16x8*)&Ks[(nt * 16 + l15) * 68 + kk + lq * 8];
                s[nt] = MFMA(a, b, s[nt]);
            }
        }
        __syncthreads();   // all waves' Ks reads done (P will overwrite)

        // ---- in-register online softmax ----
#pragma unroll
        for (int nt = 0; nt < 4; ++nt) {
            const bool valid = (kk0 + nt * 16 + l15) < nk;
#pragma unroll
            for (int i = 0; i < 4; ++i)
                s[nt][i] = valid ? s[nt][i] * scale : -INFINITY;
        }
        float al[4];
#pragma unroll
        for (int i = 0; i < 4; ++i) {
            float t = fmaxf(fmaxf(s[0][i], s[1][i]), fmaxf(s[2][i], s[3][i]));
            t = fmaxf(t, __shfl_xor(t, 1));
            t = fmaxf(t, __shfl_xor(t, 2));
            t = fmaxf(t, __shfl_xor(t, 4));
            t = fmaxf(t, __shfl_xor(t, 8));
            const float mnew = fmaxf(mrow[i], t);      // finite: >=1 valid col/row
            const float a = expf(mrow[i] - mnew);
            float ps = 0.f;
#pragma unroll
            for (int nt = 0; nt < 4; ++nt) {
                const float e = expf(s[nt][i] - mnew);  // -inf -> 0
                s[nt][i] = e; ps += e;
            }
            ps += __shfl_xor(ps, 1);
            ps += __shfl_xor(ps, 2);
            ps += __shfl_xor(ps, 4);
            ps += __shfl_xor(ps, 8);
            lrow[i] = lrow[i] * a + ps;
            mrow[i] = mnew; al[i] = a;
        }

        // ---- P into Ks (own strip; stride-68 scalar stores = 2-way free) ----
#pragma unroll
        for (int nt = 0; nt < 4; ++nt)
#pragma unroll
        for (int i = 0; i < 4; ++i)
            Ks[(wm16 + lq * 4 + i) * 68 + nt * 16 + l15] = (bf16_t)s[nt][i];

        // ---- O = O*alpha + P*V (A = own P rows — no barrier needed) ----
#pragma unroll
        for (int nt = 0; nt < 4; ++nt)
#pragma unroll
        for (int i = 0; i < 4; ++i)
            acc[nt][i] *= al[i];
#pragma unroll
        for (int kk = 0; kk < 64; kk += 32) {
            bf16x8 a = *(const bf16x8*)&Ks[(wm16 + l15) * 68 + kk + lq * 8];
#pragma unroll
            for (int nt = 0; nt < 4; ++nt) {
                bf16x8 b = *(const bf16x8*)&Vs[(nt * 16 + l15) * 68 + kk + lq * 8];
                acc[nt] = MFMA(a, b, acc[nt]);
            }
        }
    }

#pragma unroll
    for (int nt = 0; nt < 4; ++nt)
#pragma unroll
    for (int i = 0; i < 4; ++i) {
        const int r = wm16 + lq * 4 + i, qrow = q0 + r;
        if (qrow < nq)
            O[((size_t)g * nq + qrow) * ldo + hoff + nt * 16 + l15] =
                (bf16_t)(acc[nt][i] / lrow[i]);
    }
}

// ---------------------------------------------------------------------------
// Scalar attention for T2S (nk=8), bf16 in/out.
// ---------------------------------------------------------------------------
__global__ __launch_bounds__(256) void attn_k(
    const bf16_t* __restrict__ Q, int ldq,
    const bf16_t* __restrict__ Kp, int ldk,
    const bf16_t* __restrict__ Vp, int ldv,
    bf16_t* __restrict__ O, int ldo,
    int nq, int nk, float scale)
{
    __shared__ float sc[64];
    __shared__ float qv[64];
    __shared__ float red[256];
    __shared__ float s_inv;
    const int tid = threadIdx.x;
    const int bx  = blockIdx.x;
    const int qi  = bx % nq;
    const int t1  = bx / nq;
    const int h   = t1 % 12;
    const int b   = t1 / 12;
    const int hoff = h * 64;
    const size_t qrow = (size_t)b * nq + qi;
    if (tid < 64) qv[tid] = (float)Q[qrow * ldq + hoff + tid];
    __syncthreads();

    const int wave = tid >> 6, lane = tid & 63;
    const size_t kbase = (size_t)b * nk;
    for (int j = wave; j < nk; j += 4) {
        float p = (float)Kp[(kbase + j) * ldk + hoff + lane] * qv[lane];
#pragma unroll
        for (int off = 32; off > 0; off >>= 1) p += __shfl_xor(p, off);
        if (lane == 0) sc[j] = p * scale;
    }
    __syncthreads();

    float lm = -INFINITY;
    for (int j = tid; j < nk; j += 256) lm = fmaxf(lm, sc[j]);
    red[tid] = lm; __syncthreads();
    for (int s = 128; s > 0; s >>= 1) {
        if (tid < s) red[tid] = fmaxf(red[tid], red[tid + s]);
        __syncthreads();
    }
    const float mx = red[0];
    __syncthreads();
    float ls = 0.f;
    for (int j = tid; j < nk; j += 256) { float e = expf(sc[j] - mx); sc[j] = e; ls += e; }
    red[tid] = ls; __syncthreads();
    for (int s = 128; s > 0; s >>= 1) {
        if (tid < s) red[tid] += red[tid + s];
        __syncthreads();
    }
    if (tid == 0) s_inv = 1.0f / red[0];
    __syncthreads();

    const int d = tid & 63, slice = tid >> 6;
    float acc = 0.f;
    for (int j = slice; j < nk; j += 4)
        acc += sc[j] * (float)Vp[(kbase + j) * ldv + hoff + d];
    red[tid] = acc; __syncthreads();
    if (tid < 64) {
        float o = (red[tid] + red[tid + 64] + red[tid + 128] + red[tid + 192]) * s_inv;
        O[qrow * ldo + hoff + tid] = (bf16_t)o;
    }
}

// ---------------------------------------------------------------------------
// LayerNorm(768): bf16 out always, f32 out optional.
// ---------------------------------------------------------------------------
__global__ __launch_bounds__(256) void ln_k(
    const float* __restrict__ x,
    const float* __restrict__ g, const float* __restrict__ bta,
    float* __restrict__ yf, bf16_t* __restrict__ yb)
{
    __shared__ float red[256], red2[256];
    __shared__ float s_m, s_r;
    const int row = blockIdx.x, tid = threadIdx.x;
    const size_t base = (size_t)row * 768;
    const float v0 = x[base + tid];
    const float v1 = x[base + tid + 256];
    const float v2 = x[base + tid + 512];
    red[tid]  = v0 + v1 + v2;
    red2[tid] = v0 * v0 + v1 * v1 + v2 * v2;
    __syncthreads();
    for (int st = 128; st > 0; st >>= 1) {
        if (tid < st) { red[tid] += red[tid + st]; red2[tid] += red2[tid + st]; }
        __syncthreads();
    }
    if (tid == 0) {
        const float m = red[0] * (1.f / 768.f);
        const float var = red2[0] * (1.f / 768.f) - m * m;
        s_m = m; s_r = rsqrtf(var + 1e-5f);
    }
    __syncthreads();
    const float m = s_m, r = s_r;
    const float o0 = (v0 - m) * r * g[tid]       + bta[tid];
    const float o1 = (v1 - m) * r * g[tid + 256] + bta[tid + 256];
    const float o2 = (v2 - m) * r * g[tid + 512] + bta[tid + 512];
    yb[base + tid]       = (bf16_t)o0;
    yb[base + tid + 256] = (bf16_t)o1;
    yb[base + tid + 512] = (bf16_t)o2;
    if (yf) {
        yf[base + tid]       = o0;
        yf[base + tid + 256] = o1;
        yf[base + tid + 512] = o2;
    }
}

// --------------------------- elementwise helpers ---------------------------
__global__ void addpos_k(const float* __restrict__ src, const float* __restrict__ pos,
                         bf16_t* __restrict__ dst, int nrep) {
    const int row = blockIdx.x, tid = threadIdx.x;
    const size_t base = (size_t)row * 768;
    const size_t pbase = (size_t)(row % nrep) * 768;
    for (int k = 0; k < 3; ++k) {
        int c = tid + k * 256;
        dst[base + c] = (bf16_t)(src[base + c] + pos[pbase + c]);
    }
}
__global__ void t2s_prep_q(const float* __restrict__ sx, const float* __restrict__ pos,
                           bf16_t* __restrict__ dst) {
    const int row = blockIdx.x, tid = threadIdx.x;
    const int t = row & 7, bn = row >> 3, n = bn % 196, b = bn / 196;
    const size_t src = (size_t)((b * 8 + t) * 196 + n) * 768;
    const size_t dbase = (size_t)row * 768;
    const size_t pbase = (size_t)t * 768;
    for (int k = 0; k < 3; ++k) {
        int c = tid + k * 256;
        dst[dbase + c] = (bf16_t)(sx[src + c] + pos[pbase + c]);
    }
}
__global__ void t2s_prep_kv(const float* __restrict__ tcur, const float* __restrict__ pos,
                            bf16_t* __restrict__ dst) {
    const int row = blockIdx.x, tid = threadIdx.x;
    const int t = row & 7, bn = row >> 3, n = bn % 196, b = bn / 196;
    const size_t src = (size_t)(b * 1568 + t * 196 + n) * 768;
    const size_t dbase = (size_t)row * 768;
    const size_t pbase = (size_t)t * 768;
    for (int k = 0; k < 3; ++k) {
        int c = tid + k * 256;
        dst[dbase + c] = (bf16_t)(tcur[src + c] + pos[pbase + c]);
    }
}
__global__ void s_out_k(const float* __restrict__ sx, const float* __restrict__ o,
                        float* __restrict__ out) {
    const int row = blockIdx.x, tid = threadIdx.x;
    const int n = row % 196, bt = row / 196, t = bt & 7, b = bt >> 3;
    const size_t obase = (size_t)((b * 196 + n) * 8 + t) * 768;
    const size_t base = (size_t)row * 768;
    for (int k = 0; k < 3; ++k) {
        int c = tid + k * 256;
        out[base + c] = sx[base + c] + o[obase + c];
    }
}
__global__ void build_qkv_bias(const float* __restrict__ qb,
                               const float* __restrict__ vb,
                               float* __restrict__ dst) {
    int i = blockIdx.x * 256 + threadIdx.x;
    if (i < 768) dst[i] = qb[i];
    else if (i < 1536) dst[i] = 0.f;
    else if (i < 2304) dst[i] = vb[i - 1536];
}

// Weight convert: 10 f32 weights -> one bf16 arena (float4 granularity).
// cum[i] = OFF_i / 4.
struct WPtrs { const float* p[10]; };
__global__ void wcvt(WPtrs s, bf16_t* __restrict__ dst) {
    const int cum[11] = {0, 442368, 589824, 737280, 1032192, 1179648,
                         1327104, 1622016, 1769472, 2359296, 2949120};
    const int gi = blockIdx.x * 256 + threadIdx.x;
    int seg = 0;
#pragma unroll
    for (int i = 1; i < 10; ++i) if (gi >= cum[i]) seg = i;
    const float4 v = ((const float4*)s.p[seg])[gi - cum[seg]];
    bf16x4 o;
    o[0] = (bf16_t)v.x; o[1] = (bf16_t)v.y; o[2] = (bf16_t)v.z; o[3] = (bf16_t)v.w;
    ((bf16x4*)dst)[gi] = o;
}

// Arena offsets (elements)
#define OFF_QKV    0
#define OFF_APROJ  1769472
#define OFF_S2TQ   2359296
#define OFF_S2TKV  2949120
#define OFF_S2TP   4128768
#define OFF_T2SQ   4718592
#define OFF_T2SKV  5308416
#define OFF_T2SP   6488064
#define OFF_FC1    7077888
#define OFF_FC2    9437184
#define W_TOTAL    11796480

// ---------------------------------------------------------------------------
extern "C" void kernel_launch(void* const* d_in, const int* in_sizes, int n_in,
                              void* d_out, int out_size, void* d_ws, size_t ws_size,
                              hipStream_t stream)
{
    typedef const float* fp;
    fp s_x     = (fp)d_in[0];
    fp t_x     = (fp)d_in[1];
    fp g1      = (fp)d_in[2];
    fp bb1     = (fp)d_in[3];
    fp qkv_w   = (fp)d_in[4];
    fp q_bias  = (fp)d_in[5];
    fp v_bias  = (fp)d_in[6];
    fp aproj_w = (fp)d_in[7];
    fp aproj_b = (fp)d_in[8];
    fp sa_w1   = (fp)d_in[9];
    fp sa_b1   = (fp)d_in[10];
    fp sa_w2   = (fp)d_in[11];
    fp sa_b2   = (fp)d_in[12];
    fp s2t_pos_cnn  = (fp)d_in[13];
    fp s2t_pos_vmae = (fp)d_in[14];
    fp s2t_qw  = (fp)d_in[15];
    fp s2t_qb  = (fp)d_in[16];
    fp s2t_kvw = (fp)d_in[17];
    fp s2t_kvb = (fp)d_in[18];
    fp s2t_pw  = (fp)d_in[19];
    fp s2t_pb  = (fp)d_in[20];
    fp t2s_pos_cnn  = (fp)d_in[21];
    fp t2s_pos_vmae = (fp)d_in[22];
    fp t2s_qw  = (fp)d_in[23];
    fp t2s_qb  = (fp)d_in[24];
    fp t2s_kvw = (fp)d_in[25];
    fp t2s_kvb = (fp)d_in[26];
    fp t2s_pw  = (fp)d_in[27];
    fp t2s_pb  = (fp)d_in[28];
    fp g2      = (fp)d_in[29];
    fp bb2     = (fp)d_in[30];
    fp fc1_w   = (fp)d_in[31];
    fp fc1_b   = (fp)d_in[32];
    fp fc2_w   = (fp)d_in[33];
    fp fc2_b   = (fp)d_in[34];
    fp ma_w1   = (fp)d_in[35];
    fp ma_b1   = (fp)d_in[36];
    fp ma_w2   = (fp)d_in[37];
    fp ma_b2   = (fp)d_in[38];

    const size_t RD = (size_t)6272 * 768;

    float* ws   = (float*)d_ws;
    float* F    = ws;                      // aproj out / mad out
    float* G    = F + RD;                  // running t
    float* CI   = G + RD;                  // t2s_p out -> ln2 f32 out
    float* Hb   = CI + RD;                 // 6272x192 adapter hidden
    float* qkvb = Hb + (size_t)6272 * 192;
    bf16_t* BW  = (bf16_t*)(qkvb + 2304);  // weight arena
    bf16_t* Xb  = BW + W_TOTAL;            // GEMM A-input staging (RD)
    bf16_t* Eb  = Xb + RD;                 // q mirrors / flash out (RD)
    bf16_t* Fb  = Eb + RD;                 // flash/attn out (RD)
    bf16_t* MB  = Fb + RD;                 // big mirror: qkv/kv/fc1 (6272x3072)

    float* out_s = (float*)d_out;          // [32*196, 768]
    float* out_t = out_s + RD;             // [4*1568, 768]

    const dim3 blk(256);

    // ---- weight conversion ----
    WPtrs wp;
    wp.p[0] = qkv_w;  wp.p[1] = aproj_w; wp.p[2] = s2t_qw; wp.p[3] = s2t_kvw;
    wp.p[4] = s2t_pw; wp.p[5] = t2s_qw;  wp.p[6] = t2s_kvw; wp.p[7] = t2s_pw;
    wp.p[8] = fc1_w;  wp.p[9] = fc2_w;
    wcvt<<<11520, blk, 0, stream>>>(wp, BW);

    // ---- stage 1: self-attention + serial adapter ----
    ln_k<<<6272, blk, 0, stream>>>(t_x, g1, bb1, nullptr, Xb);
    build_qkv_bias<<<9, blk, 0, stream>>>(q_bias, v_bias, qkvb);
    gemm128<false><<<dim3(18, 49), blk, 0, stream>>>(
        Xb, BW + OFF_QKV, qkvb, nullptr, nullptr, 0.f, nullptr, MB, 6272, 2304, 768);
    flash_k<<<dim3(25, 12, 4), blk, 0, stream>>>(
        MB, 2304, MB + 768, 2304, MB + 1536, 2304, Eb, 768, 1568, 1568, 0.125f);
    gemm128x64<false><<<dim3(12, 49), blk, 0, stream>>>(
        Eb, BW + OFF_APROJ, aproj_b, nullptr, nullptr, 0.f, F, nullptr, 6272, 768, 768);
    gemm_bt<true><<<dim3(3, 98), blk, 0, stream>>>(
        F, sa_w1, sa_b1, nullptr, nullptr, 0.f, Hb, 6272, 192, 768);
    gemm_bt<false><<<dim3(12, 98), blk, 0, stream>>>(
        Hb, sa_w2, sa_b2, F, t_x, 1.0f, G, 6272, 768, 192);   // t1

    // ---- stage 2: S2T cross-attn ----
    addpos_k<<<6272, blk, 0, stream>>>(G, s2t_pos_vmae, Xb, 196);
    gemm128x64<false><<<dim3(12, 49), blk, 0, stream>>>(
        Xb, BW + OFF_S2TQ, s2t_qb, nullptr, nullptr, 0.f, nullptr, Eb, 6272, 768, 768);
    addpos_k<<<6272, blk, 0, stream>>>(s_x, s2t_pos_cnn, Xb, 196);
    gemm128<false><<<dim3(12, 49), blk, 0, stream>>>(
        Xb, BW + OFF_S2TKV, s2t_kvb, nullptr, nullptr, 0.f, nullptr, MB, 6272, 1536, 768);
    flash_k<<<dim3(4, 12, 32), blk, 0, stream>>>(
        Eb, 768, MB, 1536, MB + 768, 1536, Fb, 768, 196, 196, 0.125f);
    gemm128x64<false><<<dim3(12, 49), blk, 0, stream>>>(
        Fb, BW + OFF_S2TP, s2t_pb, G, nullptr, 0.f, G, nullptr, 6272, 768, 768);  // t2

    // ---- stage 3: T2S cross-attn ----
    t2s_prep_q<<<6272, blk, 0, stream>>>(s_x, t2s_pos_cnn, Xb);
    gemm128x64<false><<<dim3(12, 49), blk, 0, stream>>>(
        Xb, BW + OFF_T2SQ, t2s_qb, nullptr, nullptr, 0.f, nullptr, Eb, 6272, 768, 768);
    t2s_prep_kv<<<6272, blk, 0, stream>>>(G, t2s_pos_vmae, Xb);
    gemm128<false><<<dim3(12, 49), blk, 0, stream>>>(
        Xb, BW + OFF_T2SKV, t2s_kvb, nullptr, nullptr, 0.f, nullptr, MB, 6272, 1536, 768);
    attn_k<<<784 * 12 * 8, blk, 0, stream>>>(
        Eb, 768, MB, 1536, MB + 768, 1536, Fb, 768, 8, 8, 0.125f);
    gemm128x64<false><<<dim3(12, 49), blk, 0, stream>>>(
        Fb, BW + OFF_T2SP, t2s_pb, nullptr, nullptr, 0.f, CI, nullptr, 6272, 768, 768);
    s_out_k<<<6272, blk, 0, stream>>>(s_x, CI, out_s);

    // ---- stage 4: MLP + parallel adapter ----
    ln_k<<<6272, blk, 0, stream>>>(G, g2, bb2, CI, Xb);
    gemm128<true><<<dim3(24, 49), blk, 0, stream>>>(
        Xb, BW + OFF_FC1, fc1_b, nullptr, nullptr, 0.f, nullptr, MB, 6272, 3072, 768);
    gemm_bt<true><<<dim3(3, 98), blk, 0, stream>>>(
        CI, ma_w1, ma_b1, nullptr, nullptr, 0.f, Hb, 6272, 192, 768);
    gemm_bt<false><<<dim3(12, 98), blk, 0, stream>>>(
        Hb, ma_w2, ma_b2, nullptr, nullptr, 0.f, F, 6272, 768, 192);
    gemm128x64<false><<<dim3(12, 49), blk, 0, stream>>>(
        MB, BW + OFF_FC2, fc2_b, G, F, 0.5f, out_t, nullptr, 6272, 768, 3072);
}